// Round 5
// baseline (27056.857 us; speedup 1.0000x reference)
//
#include <hip/hip_runtime.h>
#include <cstdint>

#define EMBD 300
#define GNUM 2048
#define LSEM 10
#define VSEM 30
#define NLAY 5

// ---------------- diagnostics / utility ----------------
__global__ void k_diag(float* __restrict__ p, int n, float v) {
  int i = blockIdx.x * blockDim.x + threadIdx.x;
  if (i < n) p[i] = v;
}

__global__ void k_zero(float* __restrict__ p, int n) {
  int i = blockIdx.x * blockDim.x + threadIdx.x;
  if (i < n) p[i] = 0.f;
}

// offsets via binary search (batch is sorted)
__global__ void k_offsets(const int* __restrict__ batch, int N, int* __restrict__ off) {
  int g = blockIdx.x * blockDim.x + threadIdx.x;
  if (g > GNUM) return;
  int lo = 0, hi = N;
  while (lo < hi) { int mid = (lo + hi) >> 1; if (batch[mid] < g) lo = mid + 1; else hi = mid; }
  off[g] = lo;
}

// ---------------- hl = act(prev) + vn[batch]; tacc = (1+eps)*hl (IN PLACE over prev) ----------------
template<bool FIRST>
__global__ void k_hl(const float* __restrict__ aemb, const int* __restrict__ x_idx,
                     const float* __restrict__ scale, const float* __restrict__ shift,
                     const int* __restrict__ batch, const float* __restrict__ vn,
                     const float* __restrict__ epsArr, int l,
                     float* pt,                    // read prev-h, write tacc (same buffer)
                     float* __restrict__ hl, int N)
{
  int i = blockIdx.x;
  int c = threadIdx.x;
  if (c >= EMBD) return;
  float x;
  if (FIRST) {
    x = aemb[(size_t)x_idx[i] * EMBD + c];
  } else {
    x = pt[(size_t)i * EMBD + c];
    x = fmaxf(fmaf(x, scale[c], shift[c]), 0.f);   // BN + relu of previous layer output
  }
  float h = x + vn[(size_t)batch[i] * EMBD + c];
  hl[(size_t)i * EMBD + c] = h;
  pt[(size_t)i * EMBD + c] = (1.f + epsArr[l]) * h;
}

// ---------------- edge scatter: tacc[dst] += relu(hl[src] + bond[attr]) ----------------
__global__ void k_scatter(const int* __restrict__ src, const int* __restrict__ dst,
                          const int* __restrict__ eattr,
                          const float* __restrict__ hl, const float* __restrict__ bond,
                          float* __restrict__ tacc, int E)
{
  int wid = (blockIdx.x * blockDim.x + threadIdx.x) >> 6;
  int lane = threadIdx.x & 63;
  int nw = (gridDim.x * blockDim.x) >> 6;
  for (int e = wid; e < E; e += nw) {
    int s = src[e], d = dst[e], a = eattr[e];
    const float* hrow = hl + (size_t)s * EMBD;
    const float* brow = bond + (size_t)a * EMBD;
    float* trow = tacc + (size_t)d * EMBD;
    for (int c = lane; c < EMBD; c += 64) {
      float v = hrow[c] + brow[c];
      if (v > 0.f) atomicAdd(&trow[c], v);
    }
  }
}

// ============ 128x128-tile fp32 GEMM, 8x8 acc per thread ============
// C = act(A') @ W + bias ; A' = AFUSE ? relu(A*ascale+ashift) : A
template<bool AFUSE, bool ORELU>
__global__ __launch_bounds__(256, 3) void k_gemm128(
    const float* __restrict__ A, const float* __restrict__ W,
    const float* __restrict__ bias, float* __restrict__ C,
    int N, int K, int M,
    const float* __restrict__ ascale, const float* __restrict__ ashift)
{
  __shared__ __align__(16) float As[16][136];   // k-major, transposed A tile
  __shared__ __align__(16) float Bs[16][136];
  int tid = threadIdx.x;
  int row0 = blockIdx.x * 128;
  int col0 = blockIdx.y * 128;
  int tx = tid & 15, ty = tid >> 4;
  int arow = tid >> 1;                 // 0..127
  int akq  = (tid & 1) * 4;            // 0 or 4 ; plus +8 for second
  int bkk  = tid >> 4;                 // 0..15
  int bj   = (tid & 15) * 4;           // 0..60
  float acc[2][2][4][4] = {};
  for (int k0 = 0; k0 < K; k0 += 16) {
    bool kfull = (k0 + 16 <= K);
    // ---- A tile ----
    {
      int gr = row0 + arow;
      #pragma unroll
      for (int h = 0; h < 2; h++) {
        int kb = akq + h * 8;
        int gk = k0 + kb;
        float a0 = 0.f, a1 = 0.f, a2 = 0.f, a3 = 0.f;
        if (gr < N) {
          const float* ap = A + (size_t)gr * K + gk;
          if (kfull) {
            float4 t = *reinterpret_cast<const float4*>(ap);
            a0 = t.x; a1 = t.y; a2 = t.z; a3 = t.w;
          } else {
            if (gk + 0 < K) a0 = ap[0];
            if (gk + 1 < K) a1 = ap[1];
            if (gk + 2 < K) a2 = ap[2];
            if (gk + 3 < K) a3 = ap[3];
          }
          if (AFUSE) {
            if (kfull) {
              float4 sc = *reinterpret_cast<const float4*>(ascale + gk);
              float4 sf = *reinterpret_cast<const float4*>(ashift + gk);
              a0 = fmaxf(fmaf(a0, sc.x, sf.x), 0.f);
              a1 = fmaxf(fmaf(a1, sc.y, sf.y), 0.f);
              a2 = fmaxf(fmaf(a2, sc.z, sf.z), 0.f);
              a3 = fmaxf(fmaf(a3, sc.w, sf.w), 0.f);
            } else {
              if (gk + 0 < K) a0 = fmaxf(fmaf(a0, ascale[gk + 0], ashift[gk + 0]), 0.f);
              if (gk + 1 < K) a1 = fmaxf(fmaf(a1, ascale[gk + 1], ashift[gk + 1]), 0.f);
              if (gk + 2 < K) a2 = fmaxf(fmaf(a2, ascale[gk + 2], ashift[gk + 2]), 0.f);
              if (gk + 3 < K) a3 = fmaxf(fmaf(a3, ascale[gk + 3], ashift[gk + 3]), 0.f);
            }
          }
        }
        As[kb + 0][arow] = a0; As[kb + 1][arow] = a1;
        As[kb + 2][arow] = a2; As[kb + 3][arow] = a3;
      }
    }
    // ---- B tile ----
    {
      int gk = k0 + bkk;
      #pragma unroll
      for (int h = 0; h < 2; h++) {
        int cl = bj + h * 64;
        int gc = col0 + cl;
        float4 b4 = {0.f, 0.f, 0.f, 0.f};
        if (gk < K) {
          const float* wp = W + (size_t)gk * M + gc;
          if (gc + 3 < M) {
            b4 = *reinterpret_cast<const float4*>(wp);
          } else {
            if (gc + 0 < M) b4.x = wp[0];
            if (gc + 1 < M) b4.y = wp[1];
            if (gc + 2 < M) b4.z = wp[2];
          }
        }
        *reinterpret_cast<float4*>(&Bs[bkk][cl]) = b4;
      }
    }
    __syncthreads();
    #pragma unroll
    for (int kk = 0; kk < 16; kk++) {
      float4 a0 = *reinterpret_cast<const float4*>(&As[kk][ty * 4]);
      float4 a1 = *reinterpret_cast<const float4*>(&As[kk][64 + ty * 4]);
      float4 b0 = *reinterpret_cast<const float4*>(&Bs[kk][tx * 4]);
      float4 b1 = *reinterpret_cast<const float4*>(&Bs[kk][64 + tx * 4]);
      float ar[2][4] = {{a0.x, a0.y, a0.z, a0.w}, {a1.x, a1.y, a1.z, a1.w}};
      float br[2][4] = {{b0.x, b0.y, b0.z, b0.w}, {b1.x, b1.y, b1.z, b1.w}};
      #pragma unroll
      for (int rh = 0; rh < 2; rh++)
        #pragma unroll
        for (int u = 0; u < 4; u++)
          #pragma unroll
          for (int ch = 0; ch < 2; ch++)
            #pragma unroll
            for (int v = 0; v < 4; v++)
              acc[rh][ch][u][v] = fmaf(ar[rh][u], br[ch][v], acc[rh][ch][u][v]);
    }
    __syncthreads();
  }
  // ---- epilogue ----
  float bv[2][4];
  #pragma unroll
  for (int ch = 0; ch < 2; ch++)
    #pragma unroll
    for (int v = 0; v < 4; v++) {
      int gc = col0 + ch * 64 + tx * 4 + v;
      bv[ch][v] = (gc < M) ? bias[gc] : 0.f;
    }
  #pragma unroll
  for (int rh = 0; rh < 2; rh++)
    #pragma unroll
    for (int u = 0; u < 4; u++) {
      int gr = row0 + rh * 64 + ty * 4 + u;
      if (gr >= N) continue;
      #pragma unroll
      for (int ch = 0; ch < 2; ch++) {
        int gc0 = col0 + ch * 64 + tx * 4;
        float val[4];
        #pragma unroll
        for (int v = 0; v < 4; v++) {
          float x = acc[rh][ch][u][v] + bv[ch][v];
          if (ORELU) x = fmaxf(x, 0.f);
          val[v] = x;
        }
        if (gc0 + 3 < M) {
          float4 o = {val[0], val[1], val[2], val[3]};
          *reinterpret_cast<float4*>(C + (size_t)gr * M + gc0) = o;
        } else {
          #pragma unroll
          for (int v = 0; v < 4; v++) {
            int gc = gc0 + v;
            if (gc < M) C[(size_t)gr * M + gc] = val[v];
          }
        }
      }
    }
}

// ============ stats-only 128-tile GEMM: fp64 column sum/sumsq of A@W+bias ============
// grid: (ceil(M/128), RB). Block loops row-tiles rt = blockIdx.y += gridDim.y.
__global__ __launch_bounds__(256, 3) void k_gemm_stats128(
    const float* __restrict__ A, const float* __restrict__ W, const float* __restrict__ bias,
    int N, int K, int M, double* __restrict__ psum, double* __restrict__ psq)
{
  __shared__ __align__(16) float As[16][136];
  __shared__ __align__(16) float Bs[16][136];
  __shared__ double smd[16][128];
  int tid = threadIdx.x;
  int col0 = blockIdx.x * 128;
  int tx = tid & 15, ty = tid >> 4;
  int arow = tid >> 1;
  int akq  = (tid & 1) * 4;
  int bkk  = tid >> 4;
  int bj   = (tid & 15) * 4;
  float bv[2][4];
  #pragma unroll
  for (int ch = 0; ch < 2; ch++)
    #pragma unroll
    for (int v = 0; v < 4; v++) {
      int gc = col0 + ch * 64 + tx * 4 + v;
      bv[ch][v] = (gc < M) ? bias[gc] : 0.f;
    }
  double ds[2][4] = {}, dq[2][4] = {};
  for (int rt = blockIdx.y; rt * 128 < N; rt += gridDim.y) {
    int row0 = rt * 128;
    float acc[2][2][4][4] = {};
    for (int k0 = 0; k0 < K; k0 += 16) {
      bool kfull = (k0 + 16 <= K);
      {
        int gr = row0 + arow;
        #pragma unroll
        for (int h = 0; h < 2; h++) {
          int kb = akq + h * 8;
          int gk = k0 + kb;
          float a0 = 0.f, a1 = 0.f, a2 = 0.f, a3 = 0.f;
          if (gr < N) {
            const float* ap = A + (size_t)gr * K + gk;
            if (kfull) {
              float4 t = *reinterpret_cast<const float4*>(ap);
              a0 = t.x; a1 = t.y; a2 = t.z; a3 = t.w;
            } else {
              if (gk + 0 < K) a0 = ap[0];
              if (gk + 1 < K) a1 = ap[1];
              if (gk + 2 < K) a2 = ap[2];
              if (gk + 3 < K) a3 = ap[3];
            }
          }
          As[kb + 0][arow] = a0; As[kb + 1][arow] = a1;
          As[kb + 2][arow] = a2; As[kb + 3][arow] = a3;
        }
      }
      {
        int gk = k0 + bkk;
        #pragma unroll
        for (int h = 0; h < 2; h++) {
          int cl = bj + h * 64;
          int gc = col0 + cl;
          float4 b4 = {0.f, 0.f, 0.f, 0.f};
          if (gk < K) {
            const float* wp = W + (size_t)gk * M + gc;
            if (gc + 3 < M) {
              b4 = *reinterpret_cast<const float4*>(wp);
            } else {
              if (gc + 0 < M) b4.x = wp[0];
              if (gc + 1 < M) b4.y = wp[1];
              if (gc + 2 < M) b4.z = wp[2];
            }
          }
          *reinterpret_cast<float4*>(&Bs[bkk][cl]) = b4;
        }
      }
      __syncthreads();
      #pragma unroll
      for (int kk = 0; kk < 16; kk++) {
        float4 a0 = *reinterpret_cast<const float4*>(&As[kk][ty * 4]);
        float4 a1 = *reinterpret_cast<const float4*>(&As[kk][64 + ty * 4]);
        float4 b0 = *reinterpret_cast<const float4*>(&Bs[kk][tx * 4]);
        float4 b1 = *reinterpret_cast<const float4*>(&Bs[kk][64 + tx * 4]);
        float ar[2][4] = {{a0.x, a0.y, a0.z, a0.w}, {a1.x, a1.y, a1.z, a1.w}};
        float br[2][4] = {{b0.x, b0.y, b0.z, b0.w}, {b1.x, b1.y, b1.z, b1.w}};
        #pragma unroll
        for (int rh = 0; rh < 2; rh++)
          #pragma unroll
          for (int u = 0; u < 4; u++)
            #pragma unroll
            for (int ch = 0; ch < 2; ch++)
              #pragma unroll
              for (int v = 0; v < 4; v++)
                acc[rh][ch][u][v] = fmaf(ar[rh][u], br[ch][v], acc[rh][ch][u][v]);
      }
      __syncthreads();
    }
    // accumulate this row-tile's contribution (valid rows only)
    #pragma unroll
    for (int rh = 0; rh < 2; rh++)
      #pragma unroll
      for (int u = 0; u < 4; u++) {
        int gr = row0 + rh * 64 + ty * 4 + u;
        if (gr < N) {
          #pragma unroll
          for (int ch = 0; ch < 2; ch++)
            #pragma unroll
            for (int v = 0; v < 4; v++) {
              double x = (double)(acc[rh][ch][u][v] + bv[ch][v]);
              ds[ch][v] += x; dq[ch][v] += x * x;
            }
        }
      }
  }
  // reduce across the 16 ty groups
  #pragma unroll
  for (int ch = 0; ch < 2; ch++)
    #pragma unroll
    for (int v = 0; v < 4; v++) smd[ty][ch * 64 + tx * 4 + v] = ds[ch][v];
  __syncthreads();
  double S = 0.0;
  if (tid < 128) { for (int t = 0; t < 16; t++) S += smd[t][tid]; }
  __syncthreads();
  #pragma unroll
  for (int ch = 0; ch < 2; ch++)
    #pragma unroll
    for (int v = 0; v < 4; v++) smd[ty][ch * 64 + tx * 4 + v] = dq[ch][v];
  __syncthreads();
  if (tid < 128) {
    double Q = 0.0;
    for (int t = 0; t < 16; t++) Q += smd[t][tid];
    int gc = col0 + tid;
    if (gc < M) {
      psum[(size_t)blockIdx.y * M + gc] = S;
      psq [(size_t)blockIdx.y * M + gc] = Q;
    }
  }
}

// ---------------- 64x64 fp32 GEMM (head / vn path) ----------------
template<bool AFUSE, bool ORELU>
__global__ __launch_bounds__(256) void k_gemm(
    const float* __restrict__ A, const float* __restrict__ W,
    const float* __restrict__ bias, float* __restrict__ C,
    int N, int K, int M,
    const float* __restrict__ ascale, const float* __restrict__ ashift)
{
  __shared__ __align__(16) float As[16][72];
  __shared__ __align__(16) float Bs[16][72];
  int tid = threadIdx.x;
  int row0 = blockIdx.x * 64;
  int col0 = blockIdx.y * 64;
  int tx = tid & 15, ty = tid >> 4;
  bool kvec = ((K & 3) == 0);
  bool mvec = ((M & 3) == 0);
  float acc[4][4] = {};
  for (int k0 = 0; k0 < K; k0 += 16) {
    {
      int r = tid >> 2;
      int kq = (tid & 3) * 4;
      int gr = row0 + r;
      float a0 = 0.f, a1 = 0.f, a2 = 0.f, a3 = 0.f;
      if (gr < N) {
        const float* ap = A + (size_t)gr * K + k0 + kq;
        int k = k0 + kq;
        if (kvec && k + 3 < K) {
          float4 t = *reinterpret_cast<const float4*>(ap);
          a0 = t.x; a1 = t.y; a2 = t.z; a3 = t.w;
        } else {
          if (k + 0 < K) a0 = ap[0];
          if (k + 1 < K) a1 = ap[1];
          if (k + 2 < K) a2 = ap[2];
          if (k + 3 < K) a3 = ap[3];
        }
        if (AFUSE) {
          if (k + 0 < K) a0 = fmaxf(fmaf(a0, ascale[k + 0], ashift[k + 0]), 0.f);
          if (k + 1 < K) a1 = fmaxf(fmaf(a1, ascale[k + 1], ashift[k + 1]), 0.f);
          if (k + 2 < K) a2 = fmaxf(fmaf(a2, ascale[k + 2], ashift[k + 2]), 0.f);
          if (k + 3 < K) a3 = fmaxf(fmaf(a3, ascale[k + 3], ashift[k + 3]), 0.f);
        }
      }
      As[kq + 0][r] = a0; As[kq + 1][r] = a1; As[kq + 2][r] = a2; As[kq + 3][r] = a3;
    }
    {
      int kk = tid >> 4;
      int j = (tid & 15) * 4;
      int gk = k0 + kk;
      float4 bv = {0.f, 0.f, 0.f, 0.f};
      if (gk < K) {
        const float* wp = W + (size_t)gk * M + col0 + j;
        if (mvec && col0 + j + 3 < M) {
          bv = *reinterpret_cast<const float4*>(wp);
        } else {
          if (col0 + j + 0 < M) bv.x = wp[0];
          if (col0 + j + 1 < M) bv.y = wp[1];
          if (col0 + j + 2 < M) bv.z = wp[2];
          if (col0 + j + 3 < M) bv.w = wp[3];
        }
      }
      *reinterpret_cast<float4*>(&Bs[kk][j]) = bv;
    }
    __syncthreads();
    #pragma unroll
    for (int kk = 0; kk < 16; kk++) {
      float4 a4 = *reinterpret_cast<const float4*>(&As[kk][ty * 4]);
      float4 b4 = *reinterpret_cast<const float4*>(&Bs[kk][tx * 4]);
      float a[4] = {a4.x, a4.y, a4.z, a4.w};
      float b[4] = {b4.x, b4.y, b4.z, b4.w};
      #pragma unroll
      for (int u = 0; u < 4; u++)
        #pragma unroll
        for (int v = 0; v < 4; v++)
          acc[u][v] = fmaf(a[u], b[v], acc[u][v]);
    }
    __syncthreads();
  }
  float bv[4];
  #pragma unroll
  for (int v = 0; v < 4; v++) { int gc = col0 + tx * 4 + v; bv[v] = (gc < M) ? bias[gc] : 0.f; }
  #pragma unroll
  for (int u = 0; u < 4; u++) {
    int gr = row0 + ty * 4 + u;
    if (gr >= N) continue;
    int gc0 = col0 + tx * 4;
    float val[4];
    #pragma unroll
    for (int v = 0; v < 4; v++) {
      float x = acc[u][v] + bv[v];
      if (ORELU) x = fmaxf(x, 0.f);
      val[v] = x;
    }
    if (mvec && gc0 + 3 < M) {
      float4 o = {val[0], val[1], val[2], val[3]};
      *reinterpret_cast<float4*>(C + (size_t)gr * M + gc0) = o;
    } else {
      #pragma unroll
      for (int v = 0; v < 4; v++) {
        int gc = gc0 + v;
        if (gc < M) C[(size_t)gr * M + gc] = val[v];
      }
    }
  }
}

// ---------------- standalone column stats over a materialized matrix ----------------
__global__ void k_colstats(const float* __restrict__ X, int n, int C,
                           double* __restrict__ psum, double* __restrict__ psq)
{
  int tid = threadIdx.x;
  int col = blockIdx.x * 64 + (tid & 63);
  int rl = tid >> 6;
  double s = 0.0, q = 0.0;
  if (col < C) {
    int stride = gridDim.y * 4;
    for (int r = blockIdx.y * 4 + rl; r < n; r += stride) {
      double x = (double)X[(size_t)r * C + col];
      s += x; q += x * x;
    }
  }
  __shared__ double ls[2][4][64];
  ls[0][rl][tid & 63] = s;
  ls[1][rl][tid & 63] = q;
  __syncthreads();
  if (rl == 0 && col < C) {
    int c = tid & 63;
    double S = ls[0][0][c] + ls[0][1][c] + ls[0][2][c] + ls[0][3][c];
    double Q = ls[1][0][c] + ls[1][1][c] + ls[1][2][c] + ls[1][3][c];
    psum[(size_t)blockIdx.y * C + col] = S;
    psq [(size_t)blockIdx.y * C + col] = Q;
  }
}

// ---------------- finalize BN stats ----------------
__global__ void k_finstats(const double* __restrict__ psum, const double* __restrict__ psq,
                           int R, int M, int n,
                           const float* __restrict__ g, const float* __restrict__ b,
                           float* __restrict__ sc, float* __restrict__ sh)
{
  int j = blockIdx.x;
  int t = threadIdx.x;
  double s = 0.0, q = 0.0;
  for (int r = t; r < R; r += 256) { s += psum[(size_t)r * M + j]; q += psq[(size_t)r * M + j]; }
  __shared__ double ls[256], lq[256];
  ls[t] = s; lq[t] = q; __syncthreads();
  for (int w = 128; w > 0; w >>= 1) {
    if (t < w) { ls[t] += ls[t + w]; lq[t] += lq[t + w]; }
    __syncthreads();
  }
  if (t == 0) {
    double m = ls[0] / n;
    double v = lq[0] / n - m * m;
    double inv = 1.0 / sqrt(v + 1e-5);
    double scv = (double)g[j] * inv;
    sc[j] = (float)scv;
    sh[j] = (float)((double)b[j] - m * scv);
  }
}

// ---------------- per-graph segment sum of hl (+vn) ----------------
__global__ void k_vnseg(const float* __restrict__ hl, const int* __restrict__ off,
                        const float* __restrict__ vn, float* __restrict__ vtmp)
{
  int g = blockIdx.x;
  int c = threadIdx.x;
  if (c >= EMBD) return;
  int r0 = off[g], r1 = off[g + 1];
  float s = 0.f;
  for (int r = r0; r < r1; r++) s += hl[(size_t)r * EMBD + c];
  vtmp[(size_t)g * EMBD + c] = s + vn[(size_t)g * EMBD + c];
}

__global__ void k_vnfinal(const float* __restrict__ vnraw, const float* __restrict__ scale,
                          const float* __restrict__ shift, float* __restrict__ vn, int total)
{
  int i = blockIdx.x * blockDim.x + threadIdx.x;
  if (i >= total) return;
  int c = i % EMBD;
  vn[i] = fmaxf(fmaf(vnraw[i], scale[c], shift[c]), 0.f);
}

// ---------------- mean pool with fused BN ----------------
__global__ void k_pool(const float* __restrict__ t2, const int* __restrict__ off,
                       const float* __restrict__ scale, const float* __restrict__ shift,
                       float* __restrict__ hg)
{
  int g = blockIdx.x;
  int c = threadIdx.x;
  if (c >= EMBD) return;
  int r0 = off[g], r1 = off[g + 1];
  float s = 0.f;
  for (int r = r0; r < r1; r++) s += t2[(size_t)r * EMBD + c];
  int cnt = r1 - r0;
  float denom = (cnt > 0) ? (float)cnt : 1.f;
  hg[(size_t)g * EMBD + c] = (scale[c] * s + shift[c] * (float)cnt) / denom;
}

// ---------------- SEM head ----------------
__global__ void k_sem(const float* __restrict__ logits, const float* __restrict__ gum,
                      const float* __restrict__ selW, const float* __restrict__ selb,
                      float* __restrict__ msgw)
{
  int idx = blockIdx.x * blockDim.x + threadIdx.x;
  if (idx >= GNUM * LSEM) return;
  int g = idx / LSEM, l = idx % LSEM;
  const float* lp = logits + (size_t)g * (LSEM * VSEM) + l * VSEM;
  const float* gp = gum + (size_t)g * (LSEM * VSEM) + l * VSEM;
  float best = -1e30f; int bi = 0;
  for (int v = 0; v < VSEM; v++) {
    float y = lp[v] + gp[v];
    if (y > best) { best = y; bi = v; }
  }
  float* o = msgw + (size_t)g * (3 * LSEM) + l * 3;
  o[0] = selW[bi * 3 + 0] + selb[0];
  o[1] = selW[bi * 3 + 1] + selb[1];
  o[2] = selW[bi * 3 + 2] + selb[2];
}

// ---------------- host ----------------
template<bool AFUSE, bool ORELU>
static void gemm(const float* A, const float* W, const float* b, float* C,
                 int n, int k, int m, const float* sc, const float* sh, hipStream_t st)
{
  dim3 grid((n + 63) / 64, (m + 63) / 64);
  k_gemm<AFUSE, ORELU><<<grid, 256, 0, st>>>(A, W, b, C, n, k, m, sc, sh);
}

template<bool AFUSE, bool ORELU>
static void gemm128(const float* A, const float* W, const float* b, float* C,
                    int n, int k, int m, const float* sc, const float* sh, hipStream_t st)
{
  dim3 grid((n + 127) / 128, (m + 127) / 128);
  k_gemm128<AFUSE, ORELU><<<grid, 256, 0, st>>>(A, W, b, C, n, k, m, sc, sh);
}

extern "C" void kernel_launch(void* const* d_in, const int* in_sizes, int n_in,
                              void* d_out, int out_size, void* d_ws, size_t ws_size,
                              hipStream_t stream)
{
  const int*   x_idx     = (const int*)d_in[0];
  const int*   eidx      = (const int*)d_in[1];
  const int*   eattr     = (const int*)d_in[2];
  const int*   batch     = (const int*)d_in[3];
  const float* gumbel    = (const float*)d_in[4];
  const float* atom_emb  = (const float*)d_in[5];
  const float* bond_emb  = (const float*)d_in[6];
  const float* eps       = (const float*)d_in[7];
  const float* gin_W1    = (const float*)d_in[8];
  const float* gin_b1    = (const float*)d_in[9];
  const float* gin_bn1_g = (const float*)d_in[10];
  const float* gin_bn1_b = (const float*)d_in[11];
  const float* gin_W2    = (const float*)d_in[12];
  const float* gin_b2    = (const float*)d_in[13];
  const float* node_bn_g = (const float*)d_in[14];
  const float* node_bn_b = (const float*)d_in[15];
  const float* vn_W1     = (const float*)d_in[16];
  const float* vn_b1     = (const float*)d_in[17];
  const float* vn_bn1_g  = (const float*)d_in[18];
  const float* vn_bn1_b  = (const float*)d_in[19];
  const float* vn_W2     = (const float*)d_in[20];
  const float* vn_b2     = (const float*)d_in[21];
  const float* vn_bn2_g  = (const float*)d_in[22];
  const float* vn_bn2_b  = (const float*)d_in[23];
  const float* pre_W     = (const float*)d_in[24];
  const float* pre_b     = (const float*)d_in[25];
  const float* sel_W     = (const float*)d_in[26];
  const float* sel_b     = (const float*)d_in[27];
  const float* aft_W     = (const float*)d_in[28];
  const float* aft_b     = (const float*)d_in[29];
  const float* hW1       = (const float*)d_in[30];
  const float* hb1       = (const float*)d_in[31];
  const float* hW2       = (const float*)d_in[32];
  const float* hb2       = (const float*)d_in[33];
  const float* hW3       = (const float*)d_in[34];
  const float* hb3       = (const float*)d_in[35];

  const int N = in_sizes[0];
  const int E = in_sizes[2];
  const int RB = 128;                 // stats partial row-groups
  float* out = (float*)d_out;
  (void)n_in;

  char* ws = (char*)d_ws;
  size_t pos = 0;
  auto alloc = [&](size_t bytes) -> char* {
    char* p = ws + pos;
    pos = (pos + bytes + 255) & ~(size_t)255;
    return p;
  };
  int*    off   = (int*)   alloc((GNUM + 1) * sizeof(int));
  float*  hbuf0 = (float*) alloc((size_t)N * EMBD * 4);
  float*  hbuf1 = (float*) alloc((size_t)N * EMBD * 4);
  double* psum  = (double*)alloc((size_t)RB * 600 * 8);
  double* psq   = (double*)alloc((size_t)RB * 600 * 8);
  float*  vn    = (float*) alloc((size_t)GNUM * EMBD * 4);
  float*  vtmp  = (float*) alloc((size_t)GNUM * EMBD * 4);
  float*  vnraw = (float*) alloc((size_t)GNUM * EMBD * 4);
  float*  s1    = (float*) alloc(600 * 4);
  float*  sh1   = (float*) alloc(600 * 4);
  float*  s2    = (float*) alloc(EMBD * 4);
  float*  sh2   = (float*) alloc(EMBD * 4);
  float*  vs1   = (float*) alloc(600 * 4);
  float*  vsh1  = (float*) alloc(600 * 4);
  float*  vs2   = (float*) alloc(EMBD * 4);
  float*  vsh2  = (float*) alloc(EMBD * 4);

  // -------- HARD WORKSPACE GUARD --------
  const long long CH_MIN = 2048;      // must cover GNUM rows (v1 shares t1buf)
  size_t need_min = pos + (size_t)CH_MIN * 600 * 4 + (1u << 20);
  if (ws_size < need_min) {
    float v = 1000.f + (float)(ws_size >> 20);
    k_diag<<<(out_size + 255) / 256, 256, 0, stream>>>(out, out_size, v);
    return;
  }

  // t1 chunk buffer from remaining workspace (deterministic given ws_size)
  int CH;
  {
    size_t slack = 1u << 20;
    size_t remain = ws_size - pos - slack;
    long long ch = (long long)(remain / (600ull * 4ull));
    if (ch > 32768) ch = 32768;
    ch &= ~127LL;                       // multiple of 128 for clean tiling
    if (ch < CH_MIN) ch = CH_MIN;
    long long npad = ((long long)N + 127) & ~127LL;
    if (ch > npad && npad >= CH_MIN) ch = npad;
    CH = (int)ch;
  }
  float* t1buf = (float*)alloc((size_t)CH * 600 * 4);
  float* v1 = t1buf;                             // vn path runs after chunk loop
  // head-phase reuse (all sources dead by then):
  float* hg     = vnraw;
  float* logits = t1buf;                         // GNUM*300
  float* msgw   = t1buf + (size_t)GNUM * EMBD;   // GNUM*30
  float* dis    = vtmp;                          // GNUM*300
  float* o1     = vn;                            // GNUM*128
  float* o2     = vn + (size_t)GNUM * 128;       // GNUM*128

  k_zero<<<(GNUM * EMBD + 255) / 256, 256, 0, stream>>>(vn, GNUM * EMBD);
  k_offsets<<<(GNUM + 1 + 255) / 256, 256, 0, stream>>>(batch, N, off);

  const int* esrc = eidx;
  const int* edst = eidx + E;
  float* hb[2] = {hbuf0, hbuf1};

  for (int l = 0; l < NLAY; l++) {
    float* tac = hb[l & 1];          // prev-h in, tacc out (in place)
    float* hlb = hb[(l + 1) & 1];    // hl, then h of this layer

    if (l == 0)
      k_hl<true><<<N, 320, 0, stream>>>(atom_emb, x_idx, nullptr, nullptr, batch, vn, eps, l, tac, hlb, N);
    else
      k_hl<false><<<N, 320, 0, stream>>>(nullptr, nullptr, s2, sh2, batch, vn, eps, l, tac, hlb, N);

    k_scatter<<<2048, 256, 0, stream>>>(esrc, edst, eattr, hlb, bond_emb + (size_t)l * 5 * EMBD, tac, E);

    if (l < NLAY - 1)
      k_vnseg<<<GNUM, 320, 0, stream>>>(hlb, off, vn, vtmp);

    // BN1 stats: stats-only 128-tile GEMM over all rows (fp64 partials RB x 600)
    k_gemm_stats128<<<dim3(5, RB), 256, 0, stream>>>(tac, gin_W1 + (size_t)l * EMBD * 600,
                                                     gin_b1 + (size_t)l * 600, N, EMBD, 600, psum, psq);
    k_finstats<<<600, 256, 0, stream>>>(psum, psq, RB, 600, N,
                                        gin_bn1_g + (size_t)l * 600, gin_bn1_b + (size_t)l * 600, s1, sh1);

    // chunked GEMM1 -> t1buf -> GEMM2 (fused BN1+relu on A) -> h rows
    for (int r0 = 0; r0 < N; r0 += CH) {
      int nr = (N - r0 < CH) ? (N - r0) : CH;
      gemm128<false, false>(tac + (size_t)r0 * EMBD, gin_W1 + (size_t)l * EMBD * 600,
                            gin_b1 + (size_t)l * 600, t1buf, nr, EMBD, 600, nullptr, nullptr, stream);
      gemm128<true, false>(t1buf, gin_W2 + (size_t)l * 600 * EMBD, gin_b2 + (size_t)l * EMBD,
                           hlb + (size_t)r0 * EMBD, nr, 600, EMBD, s1, sh1, stream);
    }
    // node-BN stats over materialized h
    k_colstats<<<dim3(5, RB), 256, 0, stream>>>(hlb, N, EMBD, psum, psq);
    k_finstats<<<EMBD, 256, 0, stream>>>(psum, psq, RB, EMBD, N,
                                         node_bn_g + (size_t)l * EMBD, node_bn_b + (size_t)l * EMBD, s2, sh2);

    if (l < NLAY - 1) {
      gemm<false, false>(vtmp, vn_W1 + (size_t)l * EMBD * 600, vn_b1 + (size_t)l * 600, v1,
                         GNUM, EMBD, 600, nullptr, nullptr, stream);
      k_colstats<<<dim3(10, RB), 256, 0, stream>>>(v1, GNUM, 600, psum, psq);
      k_finstats<<<600, 256, 0, stream>>>(psum, psq, RB, 600, GNUM,
                                          vn_bn1_g + (size_t)l * 600, vn_bn1_b + (size_t)l * 600, vs1, vsh1);
      gemm<true, false>(v1, vn_W2 + (size_t)l * 600 * EMBD, vn_b2 + (size_t)l * EMBD, vnraw,
                        GNUM, 600, EMBD, vs1, vsh1, stream);
      k_colstats<<<dim3(5, RB), 256, 0, stream>>>(vnraw, GNUM, EMBD, psum, psq);
      k_finstats<<<EMBD, 256, 0, stream>>>(psum, psq, RB, EMBD, GNUM,
                                           vn_bn2_g + (size_t)l * EMBD, vn_bn2_b + (size_t)l * EMBD, vs2, vsh2);
      k_vnfinal<<<(GNUM * EMBD + 255) / 256, 256, 0, stream>>>(vnraw, vs2, vsh2, vn, GNUM * EMBD);
    }
  }

  float* lastH = hb[NLAY & 1];   // h of layer 4
  k_pool<<<GNUM, 320, 0, stream>>>(lastH, off, s2, sh2, hg);

  gemm<false, false>(hg, pre_W, pre_b, logits, GNUM, EMBD, LSEM * VSEM, nullptr, nullptr, stream);
  k_sem<<<(GNUM * LSEM + 255) / 256, 256, 0, stream>>>(logits, gumbel, sel_W, sel_b, msgw);
  gemm<false, false>(msgw, aft_W, aft_b, dis, GNUM, 3 * LSEM, EMBD, nullptr, nullptr, stream);
  gemm<false, true>(dis, hW1, hb1, o1, GNUM, EMBD, 128, nullptr, nullptr, stream);
  gemm<false, true>(o1, hW2, hb2, o2, GNUM, 128, 128, nullptr, nullptr, stream);
  gemm<false, false>(o2, hW3, hb3, out, GNUM, 128, 128, nullptr, nullptr, stream);
}

// Round 6
// 18118.057 us; speedup vs baseline: 1.4934x; 1.4934x over previous
//
#include <hip/hip_runtime.h>
#include <cstdint>

#define EMBD 300
#define GNUM 2048
#define LSEM 10
#define VSEM 30
#define NLAY 5

// ---------------- diagnostics / utility ----------------
__global__ void k_diag(float* __restrict__ p, int n, float v) {
  int i = blockIdx.x * blockDim.x + threadIdx.x;
  if (i < n) p[i] = v;
}

__global__ void k_zero(float* __restrict__ p, int n) {
  int i = blockIdx.x * blockDim.x + threadIdx.x;
  if (i < n) p[i] = 0.f;
}

// offsets via binary search (batch is sorted)
__global__ void k_offsets(const int* __restrict__ batch, int N, int* __restrict__ off) {
  int g = blockIdx.x * blockDim.x + threadIdx.x;
  if (g > GNUM) return;
  int lo = 0, hi = N;
  while (lo < hi) { int mid = (lo + hi) >> 1; if (batch[mid] < g) lo = mid + 1; else hi = mid; }
  off[g] = lo;
}

// ---------------- hl = act(prev) + vn[batch]; tacc = (1+eps)*hl (IN PLACE over prev) ----------------
template<bool FIRST>
__global__ void k_hl(const float* __restrict__ aemb, const int* __restrict__ x_idx,
                     const float* __restrict__ scale, const float* __restrict__ shift,
                     const int* __restrict__ batch, const float* __restrict__ vn,
                     const float* __restrict__ epsArr, int l,
                     float* pt,                    // read prev-h, write tacc (same buffer)
                     float* __restrict__ hl, int N)
{
  int i = blockIdx.x;
  int c = threadIdx.x;
  if (c >= EMBD) return;
  float x;
  if (FIRST) {
    x = aemb[(size_t)x_idx[i] * EMBD + c];
  } else {
    x = pt[(size_t)i * EMBD + c];
    x = fmaxf(fmaf(x, scale[c], shift[c]), 0.f);   // BN + relu of previous layer output
  }
  float h = x + vn[(size_t)batch[i] * EMBD + c];
  hl[(size_t)i * EMBD + c] = h;
  pt[(size_t)i * EMBD + c] = (1.f + epsArr[l]) * h;
}

// ---------------- edge scatter: tacc[dst] += relu(hl[src] + bond[attr]) ----------------
__global__ void k_scatter(const int* __restrict__ src, const int* __restrict__ dst,
                          const int* __restrict__ eattr,
                          const float* __restrict__ hl, const float* __restrict__ bond,
                          float* __restrict__ tacc, int E)
{
  int wid = (blockIdx.x * blockDim.x + threadIdx.x) >> 6;
  int lane = threadIdx.x & 63;
  int nw = (gridDim.x * blockDim.x) >> 6;
  for (int e = wid; e < E; e += nw) {
    int s = src[e], d = dst[e], a = eattr[e];
    const float* hrow = hl + (size_t)s * EMBD;
    const float* brow = bond + (size_t)a * EMBD;
    float* trow = tacc + (size_t)d * EMBD;
    for (int c = lane; c < EMBD; c += 64) {
      float v = hrow[c] + brow[c];
      if (v > 0.f) atomicAdd(&trow[c], v);
    }
  }
}

// ============ 128-row-tile fp32 GEMM, CHN*64 col tile, 8x(CHN*4) acc ============
// C = act(A') @ W + bias ; A' = AFUSE ? relu(A*ascale+ashift) : A
// NOTE: plain __launch_bounds__(256) — NO min-occupancy arg (round-5 spill cause).
template<int CHN, bool AFUSE, bool ORELU>
__global__ __launch_bounds__(256) void k_gemm128(
    const float* __restrict__ A, const float* __restrict__ W,
    const float* __restrict__ bias, float* __restrict__ C,
    int N, int K, int M,
    const float* __restrict__ ascale, const float* __restrict__ ashift)
{
  __shared__ __align__(16) float As[16][136];
  __shared__ __align__(16) float Bs[16][CHN * 64 + 8];
  int tid = threadIdx.x;
  int row0 = blockIdx.x * 128;
  int col0 = blockIdx.y * (CHN * 64);
  int tx = tid & 15, ty = tid >> 4;
  int arow = tid >> 1;                 // 0..127
  int akq  = (tid & 1) * 4;            // 0 or 4 ; +8 for second half
  int bkk  = tid >> 4;                 // 0..15
  int bj   = (tid & 15) * 4;           // 0..60
  float acc[2][CHN][4][4] = {};
  for (int k0 = 0; k0 < K; k0 += 16) {
    bool kfull = (k0 + 16 <= K);
    // ---- A tile: 128 rows x 16 k ----
    {
      int gr = row0 + arow;
      #pragma unroll
      for (int h = 0; h < 2; h++) {
        int kb = akq + h * 8;
        int gk = k0 + kb;
        float a0 = 0.f, a1 = 0.f, a2 = 0.f, a3 = 0.f;
        if (gr < N) {
          const float* ap = A + (size_t)gr * K + gk;
          if (kfull) {
            float4 t = *reinterpret_cast<const float4*>(ap);
            a0 = t.x; a1 = t.y; a2 = t.z; a3 = t.w;
          } else {
            if (gk + 0 < K) a0 = ap[0];
            if (gk + 1 < K) a1 = ap[1];
            if (gk + 2 < K) a2 = ap[2];
            if (gk + 3 < K) a3 = ap[3];
          }
          if (AFUSE) {
            if (kfull) {
              float4 sc = *reinterpret_cast<const float4*>(ascale + gk);
              float4 sf = *reinterpret_cast<const float4*>(ashift + gk);
              a0 = fmaxf(fmaf(a0, sc.x, sf.x), 0.f);
              a1 = fmaxf(fmaf(a1, sc.y, sf.y), 0.f);
              a2 = fmaxf(fmaf(a2, sc.z, sf.z), 0.f);
              a3 = fmaxf(fmaf(a3, sc.w, sf.w), 0.f);
            } else {
              if (gk + 0 < K) a0 = fmaxf(fmaf(a0, ascale[gk + 0], ashift[gk + 0]), 0.f);
              if (gk + 1 < K) a1 = fmaxf(fmaf(a1, ascale[gk + 1], ashift[gk + 1]), 0.f);
              if (gk + 2 < K) a2 = fmaxf(fmaf(a2, ascale[gk + 2], ashift[gk + 2]), 0.f);
              if (gk + 3 < K) a3 = fmaxf(fmaf(a3, ascale[gk + 3], ashift[gk + 3]), 0.f);
            }
          }
        }
        As[kb + 0][arow] = a0; As[kb + 1][arow] = a1;
        As[kb + 2][arow] = a2; As[kb + 3][arow] = a3;
      }
    }
    // ---- B tile: 16 k x CHN*64 cols ----
    {
      int gk = k0 + bkk;
      #pragma unroll
      for (int h = 0; h < CHN; h++) {
        int cl = bj + h * 64;
        int gc = col0 + cl;
        float4 b4 = {0.f, 0.f, 0.f, 0.f};
        if (gk < K) {
          const float* wp = W + (size_t)gk * M + gc;
          if (gc + 3 < M) {
            b4 = *reinterpret_cast<const float4*>(wp);
          } else {
            if (gc + 0 < M) b4.x = wp[0];
            if (gc + 1 < M) b4.y = wp[1];
            if (gc + 2 < M) b4.z = wp[2];
          }
        }
        *reinterpret_cast<float4*>(&Bs[bkk][cl]) = b4;
      }
    }
    __syncthreads();
    #pragma unroll
    for (int kk = 0; kk < 16; kk++) {
      float4 a0 = *reinterpret_cast<const float4*>(&As[kk][ty * 4]);
      float4 a1 = *reinterpret_cast<const float4*>(&As[kk][64 + ty * 4]);
      float ar[2][4] = {{a0.x, a0.y, a0.z, a0.w}, {a1.x, a1.y, a1.z, a1.w}};
      float br[CHN][4];
      #pragma unroll
      for (int ch = 0; ch < CHN; ch++) {
        float4 b4 = *reinterpret_cast<const float4*>(&Bs[kk][ch * 64 + tx * 4]);
        br[ch][0] = b4.x; br[ch][1] = b4.y; br[ch][2] = b4.z; br[ch][3] = b4.w;
      }
      #pragma unroll
      for (int rh = 0; rh < 2; rh++)
        #pragma unroll
        for (int u = 0; u < 4; u++)
          #pragma unroll
          for (int ch = 0; ch < CHN; ch++)
            #pragma unroll
            for (int v = 0; v < 4; v++)
              acc[rh][ch][u][v] = fmaf(ar[rh][u], br[ch][v], acc[rh][ch][u][v]);
    }
    __syncthreads();
  }
  // ---- epilogue ----
  float bv[CHN][4];
  #pragma unroll
  for (int ch = 0; ch < CHN; ch++)
    #pragma unroll
    for (int v = 0; v < 4; v++) {
      int gc = col0 + ch * 64 + tx * 4 + v;
      bv[ch][v] = (gc < M) ? bias[gc] : 0.f;
    }
  #pragma unroll
  for (int rh = 0; rh < 2; rh++)
    #pragma unroll
    for (int u = 0; u < 4; u++) {
      int gr = row0 + rh * 64 + ty * 4 + u;
      if (gr >= N) continue;
      #pragma unroll
      for (int ch = 0; ch < CHN; ch++) {
        int gc0 = col0 + ch * 64 + tx * 4;
        float val[4];
        #pragma unroll
        for (int v = 0; v < 4; v++) {
          float x = acc[rh][ch][u][v] + bv[ch][v];
          if (ORELU) x = fmaxf(x, 0.f);
          val[v] = x;
        }
        if (gc0 + 3 < M) {
          float4 o = {val[0], val[1], val[2], val[3]};
          *reinterpret_cast<float4*>(C + (size_t)gr * M + gc0) = o;
        } else {
          #pragma unroll
          for (int v = 0; v < 4; v++) {
            int gc = gc0 + v;
            if (gc < M) C[(size_t)gr * M + gc] = val[v];
          }
        }
      }
    }
}

// ---------------- 64x64 fp32 GEMM (head / vn path) — round-4 proven ----------------
template<bool AFUSE, bool ORELU>
__global__ __launch_bounds__(256) void k_gemm(
    const float* __restrict__ A, const float* __restrict__ W,
    const float* __restrict__ bias, float* __restrict__ C,
    int N, int K, int M,
    const float* __restrict__ ascale, const float* __restrict__ ashift)
{
  __shared__ __align__(16) float As[16][72];
  __shared__ __align__(16) float Bs[16][72];
  int tid = threadIdx.x;
  int row0 = blockIdx.x * 64;
  int col0 = blockIdx.y * 64;
  int tx = tid & 15, ty = tid >> 4;
  bool kvec = ((K & 3) == 0);
  bool mvec = ((M & 3) == 0);
  float acc[4][4] = {};
  for (int k0 = 0; k0 < K; k0 += 16) {
    {
      int r = tid >> 2;
      int kq = (tid & 3) * 4;
      int gr = row0 + r;
      float a0 = 0.f, a1 = 0.f, a2 = 0.f, a3 = 0.f;
      if (gr < N) {
        const float* ap = A + (size_t)gr * K + k0 + kq;
        int k = k0 + kq;
        if (kvec && k + 3 < K) {
          float4 t = *reinterpret_cast<const float4*>(ap);
          a0 = t.x; a1 = t.y; a2 = t.z; a3 = t.w;
        } else {
          if (k + 0 < K) a0 = ap[0];
          if (k + 1 < K) a1 = ap[1];
          if (k + 2 < K) a2 = ap[2];
          if (k + 3 < K) a3 = ap[3];
        }
        if (AFUSE) {
          if (k + 0 < K) a0 = fmaxf(fmaf(a0, ascale[k + 0], ashift[k + 0]), 0.f);
          if (k + 1 < K) a1 = fmaxf(fmaf(a1, ascale[k + 1], ashift[k + 1]), 0.f);
          if (k + 2 < K) a2 = fmaxf(fmaf(a2, ascale[k + 2], ashift[k + 2]), 0.f);
          if (k + 3 < K) a3 = fmaxf(fmaf(a3, ascale[k + 3], ashift[k + 3]), 0.f);
        }
      }
      As[kq + 0][r] = a0; As[kq + 1][r] = a1; As[kq + 2][r] = a2; As[kq + 3][r] = a3;
    }
    {
      int kk = tid >> 4;
      int j = (tid & 15) * 4;
      int gk = k0 + kk;
      float4 bv = {0.f, 0.f, 0.f, 0.f};
      if (gk < K) {
        const float* wp = W + (size_t)gk * M + col0 + j;
        if (mvec && col0 + j + 3 < M) {
          bv = *reinterpret_cast<const float4*>(wp);
        } else {
          if (col0 + j + 0 < M) bv.x = wp[0];
          if (col0 + j + 1 < M) bv.y = wp[1];
          if (col0 + j + 2 < M) bv.z = wp[2];
          if (col0 + j + 3 < M) bv.w = wp[3];
        }
      }
      *reinterpret_cast<float4*>(&Bs[kk][j]) = bv;
    }
    __syncthreads();
    #pragma unroll
    for (int kk = 0; kk < 16; kk++) {
      float4 a4 = *reinterpret_cast<const float4*>(&As[kk][ty * 4]);
      float4 b4 = *reinterpret_cast<const float4*>(&Bs[kk][tx * 4]);
      float a[4] = {a4.x, a4.y, a4.z, a4.w};
      float b[4] = {b4.x, b4.y, b4.z, b4.w};
      #pragma unroll
      for (int u = 0; u < 4; u++)
        #pragma unroll
        for (int v = 0; v < 4; v++)
          acc[u][v] = fmaf(a[u], b[v], acc[u][v]);
    }
    __syncthreads();
  }
  float bv[4];
  #pragma unroll
  for (int v = 0; v < 4; v++) { int gc = col0 + tx * 4 + v; bv[v] = (gc < M) ? bias[gc] : 0.f; }
  #pragma unroll
  for (int u = 0; u < 4; u++) {
    int gr = row0 + ty * 4 + u;
    if (gr >= N) continue;
    int gc0 = col0 + tx * 4;
    float val[4];
    #pragma unroll
    for (int v = 0; v < 4; v++) {
      float x = acc[u][v] + bv[v];
      if (ORELU) x = fmaxf(x, 0.f);
      val[v] = x;
    }
    if (mvec && gc0 + 3 < M) {
      float4 o = {val[0], val[1], val[2], val[3]};
      *reinterpret_cast<float4*>(C + (size_t)gr * M + gc0) = o;
    } else {
      #pragma unroll
      for (int v = 0; v < 4; v++) {
        int gc = gc0 + v;
        if (gc < M) C[(size_t)gr * M + gc] = val[v];
      }
    }
  }
}

// ---------------- stats-only 64-tile GEMM (round-4 proven, 52 VGPR) ----------------
// grid: (ceil(M/64), RB). Each block loops row-tiles rt = blockIdx.y, += gridDim.y.
__global__ __launch_bounds__(256) void k_gemm_stats(
    const float* __restrict__ A, const float* __restrict__ W, const float* __restrict__ bias,
    int N, int K, int M, double* __restrict__ psum, double* __restrict__ psq)
{
  __shared__ __align__(16) float As[16][72];
  __shared__ __align__(16) float Bs[16][72];
  __shared__ double sm[16][64];
  int tid = threadIdx.x;
  int col0 = blockIdx.x * 64;
  int tx = tid & 15, ty = tid >> 4;
  bool kvec = ((K & 3) == 0);
  float bv[4];
  #pragma unroll
  for (int v = 0; v < 4; v++) { int gc = col0 + tx * 4 + v; bv[v] = (gc < M) ? bias[gc] : 0.f; }
  double ds[4] = {0.0, 0.0, 0.0, 0.0}, dq[4] = {0.0, 0.0, 0.0, 0.0};
  for (int rt = blockIdx.y; rt * 64 < N; rt += gridDim.y) {
    int row0 = rt * 64;
    float acc[4][4] = {};
    for (int k0 = 0; k0 < K; k0 += 16) {
      {
        int r = tid >> 2;
        int kq = (tid & 3) * 4;
        int gr = row0 + r;
        float a0 = 0.f, a1 = 0.f, a2 = 0.f, a3 = 0.f;
        if (gr < N) {
          const float* ap = A + (size_t)gr * K + k0 + kq;
          int k = k0 + kq;
          if (kvec && k + 3 < K) {
            float4 t = *reinterpret_cast<const float4*>(ap);
            a0 = t.x; a1 = t.y; a2 = t.z; a3 = t.w;
          } else {
            if (k + 0 < K) a0 = ap[0];
            if (k + 1 < K) a1 = ap[1];
            if (k + 2 < K) a2 = ap[2];
            if (k + 3 < K) a3 = ap[3];
          }
        }
        As[kq + 0][r] = a0; As[kq + 1][r] = a1; As[kq + 2][r] = a2; As[kq + 3][r] = a3;
      }
      {
        int kk = tid >> 4;
        int j = (tid & 15) * 4;
        int gk = k0 + kk;
        float4 b4 = {0.f, 0.f, 0.f, 0.f};
        if (gk < K) {
          const float* wp = W + (size_t)gk * M + col0 + j;
          if (((M & 3) == 0) && col0 + j + 3 < M) {
            b4 = *reinterpret_cast<const float4*>(wp);
          } else {
            if (col0 + j + 0 < M) b4.x = wp[0];
            if (col0 + j + 1 < M) b4.y = wp[1];
            if (col0 + j + 2 < M) b4.z = wp[2];
            if (col0 + j + 3 < M) b4.w = wp[3];
          }
        }
        *reinterpret_cast<float4*>(&Bs[kk][j]) = b4;
      }
      __syncthreads();
      #pragma unroll
      for (int kk = 0; kk < 16; kk++) {
        float4 a4 = *reinterpret_cast<const float4*>(&As[kk][ty * 4]);
        float4 b4 = *reinterpret_cast<const float4*>(&Bs[kk][tx * 4]);
        float a[4] = {a4.x, a4.y, a4.z, a4.w};
        float b[4] = {b4.x, b4.y, b4.z, b4.w};
        #pragma unroll
        for (int u = 0; u < 4; u++)
          #pragma unroll
          for (int v = 0; v < 4; v++)
            acc[u][v] = fmaf(a[u], b[v], acc[u][v]);
      }
      __syncthreads();
    }
    #pragma unroll
    for (int u = 0; u < 4; u++) {
      int gr = row0 + ty * 4 + u;
      if (gr < N) {
        #pragma unroll
        for (int v = 0; v < 4; v++) {
          double x = (double)(acc[u][v] + bv[v]);
          ds[v] += x; dq[v] += x * x;
        }
      }
    }
  }
  #pragma unroll
  for (int v = 0; v < 4; v++) sm[ty][tx * 4 + v] = ds[v];
  __syncthreads();
  double S = 0.0;
  if (tid < 64) { for (int t = 0; t < 16; t++) S += sm[t][tid]; }
  __syncthreads();
  #pragma unroll
  for (int v = 0; v < 4; v++) sm[ty][tx * 4 + v] = dq[v];
  __syncthreads();
  if (tid < 64) {
    double Q = 0.0;
    for (int t = 0; t < 16; t++) Q += sm[t][tid];
    int gc = col0 + tid;
    if (gc < M) {
      psum[(size_t)blockIdx.y * M + gc] = S;
      psq [(size_t)blockIdx.y * M + gc] = Q;
    }
  }
}

// ---------------- standalone column stats over a materialized matrix ----------------
__global__ void k_colstats(const float* __restrict__ X, int n, int C,
                           double* __restrict__ psum, double* __restrict__ psq)
{
  int tid = threadIdx.x;
  int col = blockIdx.x * 64 + (tid & 63);
  int rl = tid >> 6;
  double s = 0.0, q = 0.0;
  if (col < C) {
    int stride = gridDim.y * 4;
    for (int r = blockIdx.y * 4 + rl; r < n; r += stride) {
      double x = (double)X[(size_t)r * C + col];
      s += x; q += x * x;
    }
  }
  __shared__ double ls[2][4][64];
  ls[0][rl][tid & 63] = s;
  ls[1][rl][tid & 63] = q;
  __syncthreads();
  if (rl == 0 && col < C) {
    int c = tid & 63;
    double S = ls[0][0][c] + ls[0][1][c] + ls[0][2][c] + ls[0][3][c];
    double Q = ls[1][0][c] + ls[1][1][c] + ls[1][2][c] + ls[1][3][c];
    psum[(size_t)blockIdx.y * C + col] = S;
    psq [(size_t)blockIdx.y * C + col] = Q;
  }
}

// ---------------- finalize BN stats ----------------
__global__ void k_finstats(const double* __restrict__ psum, const double* __restrict__ psq,
                           int R, int M, int n,
                           const float* __restrict__ g, const float* __restrict__ b,
                           float* __restrict__ sc, float* __restrict__ sh)
{
  int j = blockIdx.x;
  int t = threadIdx.x;
  double s = 0.0, q = 0.0;
  for (int r = t; r < R; r += 256) { s += psum[(size_t)r * M + j]; q += psq[(size_t)r * M + j]; }
  __shared__ double ls[256], lq[256];
  ls[t] = s; lq[t] = q; __syncthreads();
  for (int w = 128; w > 0; w >>= 1) {
    if (t < w) { ls[t] += ls[t + w]; lq[t] += lq[t + w]; }
    __syncthreads();
  }
  if (t == 0) {
    double m = ls[0] / n;
    double v = lq[0] / n - m * m;
    double inv = 1.0 / sqrt(v + 1e-5);
    double scv = (double)g[j] * inv;
    sc[j] = (float)scv;
    sh[j] = (float)((double)b[j] - m * scv);
  }
}

// ---------------- per-graph segment sum of hl (+vn) ----------------
__global__ void k_vnseg(const float* __restrict__ hl, const int* __restrict__ off,
                        const float* __restrict__ vn, float* __restrict__ vtmp)
{
  int g = blockIdx.x;
  int c = threadIdx.x;
  if (c >= EMBD) return;
  int r0 = off[g], r1 = off[g + 1];
  float s = 0.f;
  for (int r = r0; r < r1; r++) s += hl[(size_t)r * EMBD + c];
  vtmp[(size_t)g * EMBD + c] = s + vn[(size_t)g * EMBD + c];
}

__global__ void k_vnfinal(const float* __restrict__ vnraw, const float* __restrict__ scale,
                          const float* __restrict__ shift, float* __restrict__ vn, int total)
{
  int i = blockIdx.x * blockDim.x + threadIdx.x;
  if (i >= total) return;
  int c = i % EMBD;
  vn[i] = fmaxf(fmaf(vnraw[i], scale[c], shift[c]), 0.f);
}

// ---------------- mean pool with fused BN ----------------
__global__ void k_pool(const float* __restrict__ t2, const int* __restrict__ off,
                       const float* __restrict__ scale, const float* __restrict__ shift,
                       float* __restrict__ hg)
{
  int g = blockIdx.x;
  int c = threadIdx.x;
  if (c >= EMBD) return;
  int r0 = off[g], r1 = off[g + 1];
  float s = 0.f;
  for (int r = r0; r < r1; r++) s += t2[(size_t)r * EMBD + c];
  int cnt = r1 - r0;
  float denom = (cnt > 0) ? (float)cnt : 1.f;
  hg[(size_t)g * EMBD + c] = (scale[c] * s + shift[c] * (float)cnt) / denom;
}

// ---------------- SEM head ----------------
__global__ void k_sem(const float* __restrict__ logits, const float* __restrict__ gum,
                      const float* __restrict__ selW, const float* __restrict__ selb,
                      float* __restrict__ msgw)
{
  int idx = blockIdx.x * blockDim.x + threadIdx.x;
  if (idx >= GNUM * LSEM) return;
  int g = idx / LSEM, l = idx % LSEM;
  const float* lp = logits + (size_t)g * (LSEM * VSEM) + l * VSEM;
  const float* gp = gum + (size_t)g * (LSEM * VSEM) + l * VSEM;
  float best = -1e30f; int bi = 0;
  for (int v = 0; v < VSEM; v++) {
    float y = lp[v] + gp[v];
    if (y > best) { best = y; bi = v; }
  }
  float* o = msgw + (size_t)g * (3 * LSEM) + l * 3;
  o[0] = selW[bi * 3 + 0] + selb[0];
  o[1] = selW[bi * 3 + 1] + selb[1];
  o[2] = selW[bi * 3 + 2] + selb[2];
}

// ---------------- host ----------------
template<bool AFUSE, bool ORELU>
static void gemm(const float* A, const float* W, const float* b, float* C,
                 int n, int k, int m, const float* sc, const float* sh, hipStream_t st)
{
  dim3 grid((n + 63) / 64, (m + 63) / 64);
  k_gemm<AFUSE, ORELU><<<grid, 256, 0, st>>>(A, W, b, C, n, k, m, sc, sh);
}

template<int CHN, bool AFUSE>
static void gemmBig(const float* A, const float* W, const float* b, float* C,
                    int n, int k, int m, const float* sc, const float* sh, hipStream_t st)
{
  dim3 grid((n + 127) / 128, (m + CHN * 64 - 1) / (CHN * 64));
  k_gemm128<CHN, AFUSE, false><<<grid, 256, 0, st>>>(A, W, b, C, n, k, m, sc, sh);
}

extern "C" void kernel_launch(void* const* d_in, const int* in_sizes, int n_in,
                              void* d_out, int out_size, void* d_ws, size_t ws_size,
                              hipStream_t stream)
{
  const int*   x_idx     = (const int*)d_in[0];
  const int*   eidx      = (const int*)d_in[1];
  const int*   eattr     = (const int*)d_in[2];
  const int*   batch     = (const int*)d_in[3];
  const float* gumbel    = (const float*)d_in[4];
  const float* atom_emb  = (const float*)d_in[5];
  const float* bond_emb  = (const float*)d_in[6];
  const float* eps       = (const float*)d_in[7];
  const float* gin_W1    = (const float*)d_in[8];
  const float* gin_b1    = (const float*)d_in[9];
  const float* gin_bn1_g = (const float*)d_in[10];
  const float* gin_bn1_b = (const float*)d_in[11];
  const float* gin_W2    = (const float*)d_in[12];
  const float* gin_b2    = (const float*)d_in[13];
  const float* node_bn_g = (const float*)d_in[14];
  const float* node_bn_b = (const float*)d_in[15];
  const float* vn_W1     = (const float*)d_in[16];
  const float* vn_b1     = (const float*)d_in[17];
  const float* vn_bn1_g  = (const float*)d_in[18];
  const float* vn_bn1_b  = (const float*)d_in[19];
  const float* vn_W2     = (const float*)d_in[20];
  const float* vn_b2     = (const float*)d_in[21];
  const float* vn_bn2_g  = (const float*)d_in[22];
  const float* vn_bn2_b  = (const float*)d_in[23];
  const float* pre_W     = (const float*)d_in[24];
  const float* pre_b     = (const float*)d_in[25];
  const float* sel_W     = (const float*)d_in[26];
  const float* sel_b     = (const float*)d_in[27];
  const float* aft_W     = (const float*)d_in[28];
  const float* aft_b     = (const float*)d_in[29];
  const float* hW1       = (const float*)d_in[30];
  const float* hb1       = (const float*)d_in[31];
  const float* hW2       = (const float*)d_in[32];
  const float* hb2       = (const float*)d_in[33];
  const float* hW3       = (const float*)d_in[34];
  const float* hb3       = (const float*)d_in[35];

  const int N = in_sizes[0];
  const int E = in_sizes[2];
  const int RB = 128;                 // stats partial row-groups
  float* out = (float*)d_out;
  (void)n_in;

  char* ws = (char*)d_ws;
  size_t pos = 0;
  auto alloc = [&](size_t bytes) -> char* {
    char* p = ws + pos;
    pos = (pos + bytes + 255) & ~(size_t)255;
    return p;
  };
  int*    off   = (int*)   alloc((GNUM + 1) * sizeof(int));
  float*  hbuf0 = (float*) alloc((size_t)N * EMBD * 4);
  float*  hbuf1 = (float*) alloc((size_t)N * EMBD * 4);
  double* psum  = (double*)alloc((size_t)RB * 600 * 8);
  double* psq   = (double*)alloc((size_t)RB * 600 * 8);
  float*  vn    = (float*) alloc((size_t)GNUM * EMBD * 4);
  float*  vtmp  = (float*) alloc((size_t)GNUM * EMBD * 4);
  float*  vnraw = (float*) alloc((size_t)GNUM * EMBD * 4);
  float*  s1    = (float*) alloc(600 * 4);
  float*  sh1   = (float*) alloc(600 * 4);
  float*  s2    = (float*) alloc(EMBD * 4);
  float*  sh2   = (float*) alloc(EMBD * 4);
  float*  vs1   = (float*) alloc(600 * 4);
  float*  vsh1  = (float*) alloc(600 * 4);
  float*  vs2   = (float*) alloc(EMBD * 4);
  float*  vsh2  = (float*) alloc(EMBD * 4);

  // -------- HARD WORKSPACE GUARD --------
  const long long CH_MIN = 2048;      // must cover GNUM rows (v1 shares t1buf)
  size_t need_min = pos + (size_t)CH_MIN * 600 * 4 + (1u << 20);
  if (ws_size < need_min) {
    float v = 1000.f + (float)(ws_size >> 20);
    k_diag<<<(out_size + 255) / 256, 256, 0, stream>>>(out, out_size, v);
    return;
  }

  // t1 chunk buffer from remaining workspace (deterministic given ws_size)
  int CH;
  {
    size_t slack = 1u << 20;
    size_t remain = ws_size - pos - slack;
    long long ch = (long long)(remain / (600ull * 4ull));
    if (ch > 32768) ch = 32768;
    ch &= ~127LL;                       // multiple of 128 for clean tiling
    if (ch < CH_MIN) ch = CH_MIN;
    long long npad = ((long long)N + 127) & ~127LL;
    if (ch > npad && npad >= CH_MIN) ch = npad;
    CH = (int)ch;
  }
  float* t1buf = (float*)alloc((size_t)CH * 600 * 4);
  float* v1 = t1buf;                             // vn path runs after chunk loop
  // head-phase reuse (all sources dead by then):
  float* hg     = vnraw;
  float* logits = t1buf;                         // GNUM*300
  float* msgw   = t1buf + (size_t)GNUM * EMBD;   // GNUM*30
  float* dis    = vtmp;                          // GNUM*300
  float* o1     = vn;                            // GNUM*128
  float* o2     = vn + (size_t)GNUM * 128;       // GNUM*128

  k_zero<<<(GNUM * EMBD + 255) / 256, 256, 0, stream>>>(vn, GNUM * EMBD);
  k_offsets<<<(GNUM + 1 + 255) / 256, 256, 0, stream>>>(batch, N, off);

  const int* esrc = eidx;
  const int* edst = eidx + E;
  float* hb[2] = {hbuf0, hbuf1};

  for (int l = 0; l < NLAY; l++) {
    float* tac = hb[l & 1];          // prev-h in, tacc out (in place)
    float* hlb = hb[(l + 1) & 1];    // hl, then h of this layer

    if (l == 0)
      k_hl<true><<<N, 320, 0, stream>>>(atom_emb, x_idx, nullptr, nullptr, batch, vn, eps, l, tac, hlb, N);
    else
      k_hl<false><<<N, 320, 0, stream>>>(nullptr, nullptr, s2, sh2, batch, vn, eps, l, tac, hlb, N);

    k_scatter<<<2048, 256, 0, stream>>>(esrc, edst, eattr, hlb, bond_emb + (size_t)l * 5 * EMBD, tac, E);

    if (l < NLAY - 1)
      k_vnseg<<<GNUM, 320, 0, stream>>>(hlb, off, vn, vtmp);

    // BN1 stats: stats-only 64-tile GEMM over all rows (round-4 proven)
    k_gemm_stats<<<dim3(10, RB), 256, 0, stream>>>(tac, gin_W1 + (size_t)l * EMBD * 600,
                                                   gin_b1 + (size_t)l * 600, N, EMBD, 600, psum, psq);
    k_finstats<<<600, 256, 0, stream>>>(psum, psq, RB, 600, N,
                                        gin_bn1_g + (size_t)l * 600, gin_bn1_b + (size_t)l * 600, s1, sh1);

    // chunked GEMM1 -> t1buf -> GEMM2 (fused BN1+relu on A) using the 128-row tile kernel
    for (int r0 = 0; r0 < N; r0 += CH) {
      int nr = (N - r0 < CH) ? (N - r0) : CH;
      gemmBig<2, false>(tac + (size_t)r0 * EMBD, gin_W1 + (size_t)l * EMBD * 600,
                        gin_b1 + (size_t)l * 600, t1buf, nr, EMBD, 600, nullptr, nullptr, stream);
      gemmBig<1, true>(t1buf, gin_W2 + (size_t)l * 600 * EMBD, gin_b2 + (size_t)l * EMBD,
                       hlb + (size_t)r0 * EMBD, nr, 600, EMBD, s1, sh1, stream);
    }
    // node-BN stats over materialized h
    k_colstats<<<dim3(5, RB), 256, 0, stream>>>(hlb, N, EMBD, psum, psq);
    k_finstats<<<EMBD, 256, 0, stream>>>(psum, psq, RB, EMBD, N,
                                         node_bn_g + (size_t)l * EMBD, node_bn_b + (size_t)l * EMBD, s2, sh2);

    if (l < NLAY - 1) {
      gemm<false, false>(vtmp, vn_W1 + (size_t)l * EMBD * 600, vn_b1 + (size_t)l * 600, v1,
                         GNUM, EMBD, 600, nullptr, nullptr, stream);
      k_colstats<<<dim3(10, RB), 256, 0, stream>>>(v1, GNUM, 600, psum, psq);
      k_finstats<<<600, 256, 0, stream>>>(psum, psq, RB, 600, GNUM,
                                          vn_bn1_g + (size_t)l * 600, vn_bn1_b + (size_t)l * 600, vs1, vsh1);
      gemm<true, false>(v1, vn_W2 + (size_t)l * 600 * EMBD, vn_b2 + (size_t)l * EMBD, vnraw,
                        GNUM, 600, EMBD, vs1, vsh1, stream);
      k_colstats<<<dim3(5, RB), 256, 0, stream>>>(vnraw, GNUM, EMBD, psum, psq);
      k_finstats<<<EMBD, 256, 0, stream>>>(psum, psq, RB, EMBD, GNUM,
                                           vn_bn2_g + (size_t)l * EMBD, vn_bn2_b + (size_t)l * EMBD, vs2, vsh2);
      k_vnfinal<<<(GNUM * EMBD + 255) / 256, 256, 0, stream>>>(vnraw, vs2, vsh2, vn, GNUM * EMBD);
    }
  }

  float* lastH = hb[NLAY & 1];   // h of layer 4
  k_pool<<<GNUM, 320, 0, stream>>>(lastH, off, s2, sh2, hg);

  gemm<false, false>(hg, pre_W, pre_b, logits, GNUM, EMBD, LSEM * VSEM, nullptr, nullptr, stream);
  k_sem<<<(GNUM * LSEM + 255) / 256, 256, 0, stream>>>(logits, gumbel, sel_W, sel_b, msgw);
  gemm<false, false>(msgw, aft_W, aft_b, dis, GNUM, 3 * LSEM, EMBD, nullptr, nullptr, stream);
  gemm<false, true>(dis, hW1, hb1, o1, GNUM, EMBD, 128, nullptr, nullptr, stream);
  gemm<false, true>(o1, hW2, hb2, o2, GNUM, 128, 128, nullptr, nullptr, stream);
  gemm<false, false>(o2, hW3, hb3, out, GNUM, 128, 128, nullptr, nullptr, stream);
}

// Round 7
// 14819.078 us; speedup vs baseline: 1.8258x; 1.2226x over previous
//
#include <hip/hip_runtime.h>
#include <cstdint>

#define EMBD 300
#define GNUM 2048
#define LSEM 10
#define VSEM 30
#define NLAY 5
#define GRAM_KB 24

// ---------------- diagnostics / utility ----------------
__global__ void k_diag(float* __restrict__ p, int n, float v) {
  int i = blockIdx.x * blockDim.x + threadIdx.x;
  if (i < n) p[i] = v;
}

__global__ void k_zero(float* __restrict__ p, int n) {
  int i = blockIdx.x * blockDim.x + threadIdx.x;
  if (i < n) p[i] = 0.f;
}

// offsets via binary search (batch is sorted)
__global__ void k_offsets(const int* __restrict__ batch, int N, int* __restrict__ off) {
  int g = blockIdx.x * blockDim.x + threadIdx.x;
  if (g > GNUM) return;
  int lo = 0, hi = N;
  while (lo < hi) { int mid = (lo + hi) >> 1; if (batch[mid] < g) lo = mid + 1; else hi = mid; }
  off[g] = lo;
}

// ---------------- hl = act(prev) + vn[batch]; tacc = (1+eps)*hl (IN PLACE over prev) ----------------
template<bool FIRST>
__global__ void k_hl(const float* __restrict__ aemb, const int* __restrict__ x_idx,
                     const float* __restrict__ scale, const float* __restrict__ shift,
                     const int* __restrict__ batch, const float* __restrict__ vn,
                     const float* __restrict__ epsArr, int l,
                     float* pt,                    // read prev-h, write tacc (same buffer)
                     float* __restrict__ hl, int N)
{
  int i = blockIdx.x;
  int c = threadIdx.x;
  if (c >= EMBD) return;
  float x;
  if (FIRST) {
    x = aemb[(size_t)x_idx[i] * EMBD + c];
  } else {
    x = pt[(size_t)i * EMBD + c];
    x = fmaxf(fmaf(x, scale[c], shift[c]), 0.f);   // BN + relu of previous layer output
  }
  float h = x + vn[(size_t)batch[i] * EMBD + c];
  hl[(size_t)i * EMBD + c] = h;
  pt[(size_t)i * EMBD + c] = (1.f + epsArr[l]) * h;
}

// ---------------- edge scatter: tacc[dst] += relu(hl[src] + bond[attr]) ----------------
__global__ void k_scatter(const int* __restrict__ src, const int* __restrict__ dst,
                          const int* __restrict__ eattr,
                          const float* __restrict__ hl, const float* __restrict__ bond,
                          float* __restrict__ tacc, int E)
{
  int wid = (blockIdx.x * blockDim.x + threadIdx.x) >> 6;
  int lane = threadIdx.x & 63;
  int nw = (gridDim.x * blockDim.x) >> 6;
  for (int e = wid; e < E; e += nw) {
    int s = src[e], d = dst[e], a = eattr[e];
    const float* hrow = hl + (size_t)s * EMBD;
    const float* brow = bond + (size_t)a * EMBD;
    float* trow = tacc + (size_t)d * EMBD;
    for (int c = lane; c < EMBD; c += 64) {
      float v = hrow[c] + brow[c];
      if (v > 0.f) atomicAdd(&trow[c], v);
    }
  }
}

// ---------------- 64x64 fp32 GEMM (round-4 proven) ----------------
template<bool AFUSE, bool ORELU>
__global__ __launch_bounds__(256) void k_gemm(
    const float* __restrict__ A, const float* __restrict__ W,
    const float* __restrict__ bias, float* __restrict__ C,
    int N, int K, int M,
    const float* __restrict__ ascale, const float* __restrict__ ashift)
{
  __shared__ __align__(16) float As[16][72];
  __shared__ __align__(16) float Bs[16][72];
  int tid = threadIdx.x;
  int row0 = blockIdx.x * 64;
  int col0 = blockIdx.y * 64;
  int tx = tid & 15, ty = tid >> 4;
  bool kvec = ((K & 3) == 0);
  bool mvec = ((M & 3) == 0);
  float acc[4][4] = {};
  for (int k0 = 0; k0 < K; k0 += 16) {
    {
      int r = tid >> 2;
      int kq = (tid & 3) * 4;
      int gr = row0 + r;
      float a0 = 0.f, a1 = 0.f, a2 = 0.f, a3 = 0.f;
      if (gr < N) {
        const float* ap = A + (size_t)gr * K + k0 + kq;
        int k = k0 + kq;
        if (kvec && k + 3 < K) {
          float4 t = *reinterpret_cast<const float4*>(ap);
          a0 = t.x; a1 = t.y; a2 = t.z; a3 = t.w;
        } else {
          if (k + 0 < K) a0 = ap[0];
          if (k + 1 < K) a1 = ap[1];
          if (k + 2 < K) a2 = ap[2];
          if (k + 3 < K) a3 = ap[3];
        }
        if (AFUSE) {
          if (k + 0 < K) a0 = fmaxf(fmaf(a0, ascale[k + 0], ashift[k + 0]), 0.f);
          if (k + 1 < K) a1 = fmaxf(fmaf(a1, ascale[k + 1], ashift[k + 1]), 0.f);
          if (k + 2 < K) a2 = fmaxf(fmaf(a2, ascale[k + 2], ashift[k + 2]), 0.f);
          if (k + 3 < K) a3 = fmaxf(fmaf(a3, ascale[k + 3], ashift[k + 3]), 0.f);
        }
      }
      As[kq + 0][r] = a0; As[kq + 1][r] = a1; As[kq + 2][r] = a2; As[kq + 3][r] = a3;
    }
    {
      int kk = tid >> 4;
      int j = (tid & 15) * 4;
      int gk = k0 + kk;
      float4 bv = {0.f, 0.f, 0.f, 0.f};
      if (gk < K) {
        const float* wp = W + (size_t)gk * M + col0 + j;
        if (mvec && col0 + j + 3 < M) {
          bv = *reinterpret_cast<const float4*>(wp);
        } else {
          if (col0 + j + 0 < M) bv.x = wp[0];
          if (col0 + j + 1 < M) bv.y = wp[1];
          if (col0 + j + 2 < M) bv.z = wp[2];
          if (col0 + j + 3 < M) bv.w = wp[3];
        }
      }
      *reinterpret_cast<float4*>(&Bs[kk][j]) = bv;
    }
    __syncthreads();
    #pragma unroll
    for (int kk = 0; kk < 16; kk++) {
      float4 a4 = *reinterpret_cast<const float4*>(&As[kk][ty * 4]);
      float4 b4 = *reinterpret_cast<const float4*>(&Bs[kk][tx * 4]);
      float a[4] = {a4.x, a4.y, a4.z, a4.w};
      float b[4] = {b4.x, b4.y, b4.z, b4.w};
      #pragma unroll
      for (int u = 0; u < 4; u++)
        #pragma unroll
        for (int v = 0; v < 4; v++)
          acc[u][v] = fmaf(a[u], b[v], acc[u][v]);
    }
    __syncthreads();
  }
  float bv[4];
  #pragma unroll
  for (int v = 0; v < 4; v++) { int gc = col0 + tx * 4 + v; bv[v] = (gc < M) ? bias[gc] : 0.f; }
  #pragma unroll
  for (int u = 0; u < 4; u++) {
    int gr = row0 + ty * 4 + u;
    if (gr >= N) continue;
    int gc0 = col0 + tx * 4;
    float val[4];
    #pragma unroll
    for (int v = 0; v < 4; v++) {
      float x = acc[u][v] + bv[v];
      if (ORELU) x = fmaxf(x, 0.f);
      val[v] = x;
    }
    if (mvec && gc0 + 3 < M) {
      float4 o = {val[0], val[1], val[2], val[3]};
      *reinterpret_cast<float4*>(C + (size_t)gr * M + gc0) = o;
    } else {
      #pragma unroll
      for (int v = 0; v < 4; v++) {
        int gc = gc0 + v;
        if (gc < M) C[(size_t)gr * M + gc] = val[v];
      }
    }
  }
}

// ---------------- Gram: gpart[kb][tile][64][64] += A[:,I]^T A[:,J] (upper-tri tiles) ----------------
// fp32 inner (128 rows) + fp64 outer accumulation. grid (15, GRAM_KB), block 256.
__global__ __launch_bounds__(256) void k_gram(const float* __restrict__ A, int N,
                                              double* __restrict__ gpart)
{
  int bx = blockIdx.x;
  int ti = 0;
  {
    const int o1 = 5, o2 = 9, o3 = 12, o4 = 14;
    if (bx >= o1) ti = 1;
    if (bx >= o2) ti = 2;
    if (bx >= o3) ti = 3;
    if (bx >= o4) ti = 4;
  }
  const int offs[5] = {0, 5, 9, 12, 14};
  int tj = ti + (bx - offs[ti]);
  int I = ti * 64, J = tj * 64;
  __shared__ __align__(16) float LI[128][68];
  __shared__ __align__(16) float LJ[128][68];
  int tid = threadIdx.x;
  int tx = tid & 15, ty = tid >> 4;
  double dacc[4][4] = {};
  for (int rb = blockIdx.y; rb * 128 < N; rb += gridDim.y) {
    int r0 = rb * 128;
    {
      int rbase = tid >> 4;          // 0..15
      int c4 = (tid & 15) * 4;       // 0..60
      #pragma unroll
      for (int s = 0; s < 8; s++) {
        int r = rbase + s * 16;
        int gr = r0 + r;
        float4 vi = {0.f, 0.f, 0.f, 0.f}, vj = {0.f, 0.f, 0.f, 0.f};
        if (gr < N) {
          int ci = I + c4;
          if (ci + 3 < EMBD) vi = *reinterpret_cast<const float4*>(A + (size_t)gr * EMBD + ci);
          int cj = J + c4;
          if (cj + 3 < EMBD) vj = *reinterpret_cast<const float4*>(A + (size_t)gr * EMBD + cj);
        }
        *reinterpret_cast<float4*>(&LI[r][c4]) = vi;
        *reinterpret_cast<float4*>(&LJ[r][c4]) = vj;
      }
    }
    __syncthreads();
    float facc[4][4] = {};
    #pragma unroll 2
    for (int k = 0; k < 128; k++) {
      float4 a4 = *reinterpret_cast<const float4*>(&LI[k][ty * 4]);
      float4 b4 = *reinterpret_cast<const float4*>(&LJ[k][tx * 4]);
      float a[4] = {a4.x, a4.y, a4.z, a4.w};
      float b[4] = {b4.x, b4.y, b4.z, b4.w};
      #pragma unroll
      for (int u = 0; u < 4; u++)
        #pragma unroll
        for (int v = 0; v < 4; v++)
          facc[u][v] = fmaf(a[u], b[v], facc[u][v]);
    }
    #pragma unroll
    for (int u = 0; u < 4; u++)
      #pragma unroll
      for (int v = 0; v < 4; v++)
        dacc[u][v] += (double)facc[u][v];
    __syncthreads();
  }
  size_t base = ((size_t)blockIdx.y * 15 + bx) * 4096;
  #pragma unroll
  for (int u = 0; u < 4; u++)
    #pragma unroll
    for (int v = 0; v < 4; v++)
      gpart[base + (size_t)(ty * 4 + u) * 64 + tx * 4 + v] = dacc[u][v];
}

// ---------------- reduce Gram partials -> full symmetric G[300][300] ----------------
__global__ void k_gramfin(const double* __restrict__ gpart, double* __restrict__ G)
{
  int e = blockIdx.x * 256 + threadIdx.x;
  if (e >= 15 * 4096) return;
  int tile = e >> 12;
  int ii = (e >> 6) & 63, jj = e & 63;
  const int tit[15] = {0,0,0,0,0,1,1,1,1,2,2,2,3,3,4};
  const int tjt[15] = {0,1,2,3,4,1,2,3,4,2,3,4,3,4,4};
  int gi = tit[tile] * 64 + ii, gj = tjt[tile] * 64 + jj;
  if (gi >= EMBD || gj >= EMBD) return;
  double s = 0.0;
  for (int kb = 0; kb < GRAM_KB; kb++)
    s += gpart[((size_t)kb * 15 + tile) * 4096 + ii * 64 + jj];
  G[(size_t)gi * EMBD + gj] = s;
  G[(size_t)gj * EMBD + gi] = s;
}

// ---------------- BN1 scale/shift from Gram: per output column j ----------------
// S_j = c.w_j + n*b1_j ; Q_j = w_j^T G w_j + 2 b1_j (c.w_j) + n b1_j^2
__global__ void k_bn1gram(const double* __restrict__ G, const double* __restrict__ cbuf,
                          const float* __restrict__ W1, const float* __restrict__ b1,
                          const float* __restrict__ g, const float* __restrict__ b,
                          int n, float* __restrict__ sc, float* __restrict__ sh)
{
  int j = blockIdx.x;
  int t = threadIdx.x;
  __shared__ double ws[EMBD];
  __shared__ double red[256];
  for (int k = t; k < EMBD; k += 256) ws[k] = (double)W1[(size_t)k * 600 + j];
  __syncthreads();
  int i1 = 256 + t;
  double y0 = 0.0, y1 = 0.0;
  for (int k = 0; k < EMBD; k++) {
    double wk = ws[k];
    y0 += G[(size_t)k * EMBD + t] * wk;
    if (i1 < EMBD) y1 += G[(size_t)k * EMBD + i1] * wk;
  }
  double part = ws[t] * y0 + ((i1 < EMBD) ? ws[i1] * y1 : 0.0);
  double dpart = cbuf[t] * ws[t] + ((i1 < EMBD) ? cbuf[i1] * ws[i1] : 0.0);
  red[t] = part; __syncthreads();
  for (int w = 128; w > 0; w >>= 1) { if (t < w) red[t] += red[t + w]; __syncthreads(); }
  double Q = red[0]; __syncthreads();
  red[t] = dpart; __syncthreads();
  for (int w = 128; w > 0; w >>= 1) { if (t < w) red[t] += red[t + w]; __syncthreads(); }
  if (t == 0) {
    double d = red[0];
    double bj = (double)b1[j];
    double S = d + (double)n * bj;
    double Qf = Q + 2.0 * bj * d + (double)n * bj * bj;
    double m = S / n;
    double var = Qf / n - m * m;
    double inv = 1.0 / sqrt(var + 1e-5);
    double scv = (double)g[j] * inv;
    sc[j] = (float)scv;
    sh[j] = (float)((double)b[j] - m * scv);
  }
}

// ---------------- standalone column stats over a materialized matrix ----------------
__global__ void k_colstats(const float* __restrict__ X, int n, int C,
                           double* __restrict__ psum, double* __restrict__ psq)
{
  int tid = threadIdx.x;
  int col = blockIdx.x * 64 + (tid & 63);
  int rl = tid >> 6;
  double s = 0.0, q = 0.0;
  if (col < C) {
    int stride = gridDim.y * 4;
    for (int r = blockIdx.y * 4 + rl; r < n; r += stride) {
      double x = (double)X[(size_t)r * C + col];
      s += x; q += x * x;
    }
  }
  __shared__ double ls[2][4][64];
  ls[0][rl][tid & 63] = s;
  ls[1][rl][tid & 63] = q;
  __syncthreads();
  if (rl == 0 && col < C) {
    int c = tid & 63;
    double S = ls[0][0][c] + ls[0][1][c] + ls[0][2][c] + ls[0][3][c];
    double Q = ls[1][0][c] + ls[1][1][c] + ls[1][2][c] + ls[1][3][c];
    psum[(size_t)blockIdx.y * C + col] = S;
    psq [(size_t)blockIdx.y * C + col] = Q;
  }
}

// ---------------- reduce psum partials (R rows) -> cbuf (fp64 colsum) ----------------
__global__ void k_redcol(const double* __restrict__ psum, int R, int C, double* __restrict__ cbuf)
{
  int c = blockIdx.x * blockDim.x + threadIdx.x;
  if (c >= C) return;
  double s = 0.0;
  for (int r = 0; r < R; r++) s += psum[(size_t)r * C + c];
  cbuf[c] = s;
}

// ---------------- finalize BN stats ----------------
__global__ void k_finstats(const double* __restrict__ psum, const double* __restrict__ psq,
                           int R, int M, int n,
                           const float* __restrict__ g, const float* __restrict__ b,
                           float* __restrict__ sc, float* __restrict__ sh)
{
  int j = blockIdx.x;
  int t = threadIdx.x;
  double s = 0.0, q = 0.0;
  for (int r = t; r < R; r += 256) { s += psum[(size_t)r * M + j]; q += psq[(size_t)r * M + j]; }
  __shared__ double ls[256], lq[256];
  ls[t] = s; lq[t] = q; __syncthreads();
  for (int w = 128; w > 0; w >>= 1) {
    if (t < w) { ls[t] += ls[t + w]; lq[t] += lq[t + w]; }
    __syncthreads();
  }
  if (t == 0) {
    double m = ls[0] / n;
    double v = lq[0] / n - m * m;
    double inv = 1.0 / sqrt(v + 1e-5);
    double scv = (double)g[j] * inv;
    sc[j] = (float)scv;
    sh[j] = (float)((double)b[j] - m * scv);
  }
}

// ---------------- per-graph segment sum of hl (+vn) ----------------
__global__ void k_vnseg(const float* __restrict__ hl, const int* __restrict__ off,
                        const float* __restrict__ vn, float* __restrict__ vtmp)
{
  int g = blockIdx.x;
  int c = threadIdx.x;
  if (c >= EMBD) return;
  int r0 = off[g], r1 = off[g + 1];
  float s = 0.f;
  for (int r = r0; r < r1; r++) s += hl[(size_t)r * EMBD + c];
  vtmp[(size_t)g * EMBD + c] = s + vn[(size_t)g * EMBD + c];
}

__global__ void k_vnfinal(const float* __restrict__ vnraw, const float* __restrict__ scale,
                          const float* __restrict__ shift, float* __restrict__ vn, int total)
{
  int i = blockIdx.x * blockDim.x + threadIdx.x;
  if (i >= total) return;
  int c = i % EMBD;
  vn[i] = fmaxf(fmaf(vnraw[i], scale[c], shift[c]), 0.f);
}

// ---------------- mean pool with fused BN ----------------
__global__ void k_pool(const float* __restrict__ t2, const int* __restrict__ off,
                       const float* __restrict__ scale, const float* __restrict__ shift,
                       float* __restrict__ hg)
{
  int g = blockIdx.x;
  int c = threadIdx.x;
  if (c >= EMBD) return;
  int r0 = off[g], r1 = off[g + 1];
  float s = 0.f;
  for (int r = r0; r < r1; r++) s += t2[(size_t)r * EMBD + c];
  int cnt = r1 - r0;
  float denom = (cnt > 0) ? (float)cnt : 1.f;
  hg[(size_t)g * EMBD + c] = (scale[c] * s + shift[c] * (float)cnt) / denom;
}

// ---------------- SEM head ----------------
__global__ void k_sem(const float* __restrict__ logits, const float* __restrict__ gum,
                      const float* __restrict__ selW, const float* __restrict__ selb,
                      float* __restrict__ msgw)
{
  int idx = blockIdx.x * blockDim.x + threadIdx.x;
  if (idx >= GNUM * LSEM) return;
  int g = idx / LSEM, l = idx % LSEM;
  const float* lp = logits + (size_t)g * (LSEM * VSEM) + l * VSEM;
  const float* gp = gum + (size_t)g * (LSEM * VSEM) + l * VSEM;
  float best = -1e30f; int bi = 0;
  for (int v = 0; v < VSEM; v++) {
    float y = lp[v] + gp[v];
    if (y > best) { best = y; bi = v; }
  }
  float* o = msgw + (size_t)g * (3 * LSEM) + l * 3;
  o[0] = selW[bi * 3 + 0] + selb[0];
  o[1] = selW[bi * 3 + 1] + selb[1];
  o[2] = selW[bi * 3 + 2] + selb[2];
}

// ---------------- host ----------------
template<bool AFUSE, bool ORELU>
static void gemm(const float* A, const float* W, const float* b, float* C,
                 int n, int k, int m, const float* sc, const float* sh, hipStream_t st)
{
  dim3 grid((n + 63) / 64, (m + 63) / 64);
  k_gemm<AFUSE, ORELU><<<grid, 256, 0, st>>>(A, W, b, C, n, k, m, sc, sh);
}

extern "C" void kernel_launch(void* const* d_in, const int* in_sizes, int n_in,
                              void* d_out, int out_size, void* d_ws, size_t ws_size,
                              hipStream_t stream)
{
  const int*   x_idx     = (const int*)d_in[0];
  const int*   eidx      = (const int*)d_in[1];
  const int*   eattr     = (const int*)d_in[2];
  const int*   batch     = (const int*)d_in[3];
  const float* gumbel    = (const float*)d_in[4];
  const float* atom_emb  = (const float*)d_in[5];
  const float* bond_emb  = (const float*)d_in[6];
  const float* eps       = (const float*)d_in[7];
  const float* gin_W1    = (const float*)d_in[8];
  const float* gin_b1    = (const float*)d_in[9];
  const float* gin_bn1_g = (const float*)d_in[10];
  const float* gin_bn1_b = (const float*)d_in[11];
  const float* gin_W2    = (const float*)d_in[12];
  const float* gin_b2    = (const float*)d_in[13];
  const float* node_bn_g = (const float*)d_in[14];
  const float* node_bn_b = (const float*)d_in[15];
  const float* vn_W1     = (const float*)d_in[16];
  const float* vn_b1     = (const float*)d_in[17];
  const float* vn_bn1_g  = (const float*)d_in[18];
  const float* vn_bn1_b  = (const float*)d_in[19];
  const float* vn_W2     = (const float*)d_in[20];
  const float* vn_b2     = (const float*)d_in[21];
  const float* vn_bn2_g  = (const float*)d_in[22];
  const float* vn_bn2_b  = (const float*)d_in[23];
  const float* pre_W     = (const float*)d_in[24];
  const float* pre_b     = (const float*)d_in[25];
  const float* sel_W     = (const float*)d_in[26];
  const float* sel_b     = (const float*)d_in[27];
  const float* aft_W     = (const float*)d_in[28];
  const float* aft_b     = (const float*)d_in[29];
  const float* hW1       = (const float*)d_in[30];
  const float* hb1       = (const float*)d_in[31];
  const float* hW2       = (const float*)d_in[32];
  const float* hb2       = (const float*)d_in[33];
  const float* hW3       = (const float*)d_in[34];
  const float* hb3       = (const float*)d_in[35];

  const int N = in_sizes[0];
  const int E = in_sizes[2];
  const int RB = 128;                 // stats partial row-groups
  float* out = (float*)d_out;
  (void)n_in;

  char* ws = (char*)d_ws;
  size_t pos = 0;
  auto alloc = [&](size_t bytes) -> char* {
    char* p = ws + pos;
    pos = (pos + bytes + 255) & ~(size_t)255;
    return p;
  };
  int*    off   = (int*)   alloc((GNUM + 1) * sizeof(int));
  float*  hbuf0 = (float*) alloc((size_t)N * EMBD * 4);
  float*  hbuf1 = (float*) alloc((size_t)N * EMBD * 4);
  double* psum  = (double*)alloc((size_t)RB * 600 * 8);
  double* psq   = (double*)alloc((size_t)RB * 600 * 8);
  float*  vn    = (float*) alloc((size_t)GNUM * EMBD * 4);
  float*  vtmp  = (float*) alloc((size_t)GNUM * EMBD * 4);
  float*  vnraw = (float*) alloc((size_t)GNUM * EMBD * 4);
  double* cbuf  = (double*)alloc(EMBD * 8);
  float*  s1    = (float*) alloc(600 * 4);
  float*  sh1   = (float*) alloc(600 * 4);
  float*  s2    = (float*) alloc(EMBD * 4);
  float*  sh2   = (float*) alloc(EMBD * 4);
  float*  vs1   = (float*) alloc(600 * 4);
  float*  vsh1  = (float*) alloc(600 * 4);
  float*  vs2   = (float*) alloc(EMBD * 4);
  float*  vsh2  = (float*) alloc(EMBD * 4);

  // -------- region: Gram partials + G (stats phase) ALIASED with t1buf (chunk phase) --------
  const size_t gpartBytes = (size_t)GRAM_KB * 15 * 4096 * 8;       // 11.8 MB
  const size_t gBytes     = (size_t)EMBD * EMBD * 8;               // 0.72 MB
  const long long CH_MIN  = 2048;                                  // v1 needs GNUM rows
  size_t slack = 1u << 20;
  size_t region_need = gpartBytes + gBytes;
  size_t t1_min = (size_t)CH_MIN * 600 * 4;
  if (region_need < t1_min) region_need = t1_min;

  // -------- HARD WORKSPACE GUARD --------
  if (ws_size < pos + region_need + slack) {
    float v = 1000.f + (float)(ws_size >> 20);
    k_diag<<<(out_size + 255) / 256, 256, 0, stream>>>(out, out_size, v);
    return;
  }

  size_t regionBytes = ws_size - pos - slack;
  char* region = ws + pos;
  double* gpart = (double*)region;
  double* G     = (double*)(region + gpartBytes);
  float*  t1buf = (float*)region;          // aliased: phases are disjoint in time
  int CH;
  {
    long long ch = (long long)(regionBytes / (600ull * 4ull));
    if (ch > 32768) ch = 32768;
    ch &= ~63LL;
    if (ch < CH_MIN) ch = CH_MIN;
    long long npad = ((long long)N + 63) & ~63LL;
    if (ch > npad && npad >= CH_MIN) ch = npad;
    CH = (int)ch;
  }
  float* v1 = t1buf;                             // vn path runs after chunk loop
  // head-phase reuse (all sources dead by then):
  float* hg     = vnraw;
  float* logits = t1buf;                         // GNUM*300
  float* msgw   = t1buf + (size_t)GNUM * EMBD;   // GNUM*30
  float* dis    = vtmp;                          // GNUM*300
  float* o1     = vn;                            // GNUM*128
  float* o2     = vn + (size_t)GNUM * 128;       // GNUM*128

  k_zero<<<(GNUM * EMBD + 255) / 256, 256, 0, stream>>>(vn, GNUM * EMBD);
  k_offsets<<<(GNUM + 1 + 255) / 256, 256, 0, stream>>>(batch, N, off);

  const int* esrc = eidx;
  const int* edst = eidx + E;
  float* hb[2] = {hbuf0, hbuf1};

  for (int l = 0; l < NLAY; l++) {
    float* tac = hb[l & 1];          // prev-h in, tacc out (in place)
    float* hlb = hb[(l + 1) & 1];    // hl, then h of this layer

    if (l == 0)
      k_hl<true><<<N, 320, 0, stream>>>(atom_emb, x_idx, nullptr, nullptr, batch, vn, eps, l, tac, hlb, N);
    else
      k_hl<false><<<N, 320, 0, stream>>>(nullptr, nullptr, s2, sh2, batch, vn, eps, l, tac, hlb, N);

    k_scatter<<<2048, 256, 0, stream>>>(esrc, edst, eattr, hlb, bond_emb + (size_t)l * 5 * EMBD, tac, E);

    if (l < NLAY - 1)
      k_vnseg<<<GNUM, 320, 0, stream>>>(hlb, off, vn, vtmp);

    // ---- BN1 stats via Gram identity (no stats GEMM) ----
    k_colstats<<<dim3(5, RB), 256, 0, stream>>>(tac, N, EMBD, psum, psq);       // colsum partials
    k_redcol<<<2, 256, 0, stream>>>(psum, RB, EMBD, cbuf);                      // c = colsum(tacc)
    k_gram<<<dim3(15, GRAM_KB), 256, 0, stream>>>(tac, N, gpart);
    k_gramfin<<<240, 256, 0, stream>>>(gpart, G);
    k_bn1gram<<<600, 256, 0, stream>>>(G, cbuf, gin_W1 + (size_t)l * EMBD * 600,
                                       gin_b1 + (size_t)l * 600,
                                       gin_bn1_g + (size_t)l * 600, gin_bn1_b + (size_t)l * 600,
                                       N, s1, sh1);

    // chunked GEMM1 -> t1buf -> GEMM2 (fused BN1+relu on A) -> h rows
    for (int r0 = 0; r0 < N; r0 += CH) {
      int nr = (N - r0 < CH) ? (N - r0) : CH;
      gemm<false, false>(tac + (size_t)r0 * EMBD, gin_W1 + (size_t)l * EMBD * 600,
                         gin_b1 + (size_t)l * 600, t1buf, nr, EMBD, 600, nullptr, nullptr, stream);
      gemm<true, false>(t1buf, gin_W2 + (size_t)l * 600 * EMBD, gin_b2 + (size_t)l * EMBD,
                        hlb + (size_t)r0 * EMBD, nr, 600, EMBD, s1, sh1, stream);
    }
    // node-BN stats over materialized h
    k_colstats<<<dim3(5, RB), 256, 0, stream>>>(hlb, N, EMBD, psum, psq);
    k_finstats<<<EMBD, 256, 0, stream>>>(psum, psq, RB, EMBD, N,
                                         node_bn_g + (size_t)l * EMBD, node_bn_b + (size_t)l * EMBD, s2, sh2);

    if (l < NLAY - 1) {
      gemm<false, false>(vtmp, vn_W1 + (size_t)l * EMBD * 600, vn_b1 + (size_t)l * 600, v1,
                         GNUM, EMBD, 600, nullptr, nullptr, stream);
      k_colstats<<<dim3(10, RB), 256, 0, stream>>>(v1, GNUM, 600, psum, psq);
      k_finstats<<<600, 256, 0, stream>>>(psum, psq, RB, 600, GNUM,
                                          vn_bn1_g + (size_t)l * 600, vn_bn1_b + (size_t)l * 600, vs1, vsh1);
      gemm<true, false>(v1, vn_W2 + (size_t)l * 600 * EMBD, vn_b2 + (size_t)l * EMBD, vnraw,
                        GNUM, 600, EMBD, vs1, vsh1, stream);
      k_colstats<<<dim3(5, RB), 256, 0, stream>>>(vnraw, GNUM, EMBD, psum, psq);
      k_finstats<<<EMBD, 256, 0, stream>>>(psum, psq, RB, EMBD, GNUM,
                                           vn_bn2_g + (size_t)l * EMBD, vn_bn2_b + (size_t)l * EMBD, vs2, vsh2);
      k_vnfinal<<<(GNUM * EMBD + 255) / 256, 256, 0, stream>>>(vnraw, vs2, vsh2, vn, GNUM * EMBD);
    }
  }

  float* lastH = hb[NLAY & 1];   // h of layer 4
  k_pool<<<GNUM, 320, 0, stream>>>(lastH, off, s2, sh2, hg);

  gemm<false, false>(hg, pre_W, pre_b, logits, GNUM, EMBD, LSEM * VSEM, nullptr, nullptr, stream);
  k_sem<<<(GNUM * LSEM + 255) / 256, 256, 0, stream>>>(logits, gumbel, sel_W, sel_b, msgw);
  gemm<false, false>(msgw, aft_W, aft_b, dis, GNUM, 3 * LSEM, EMBD, nullptr, nullptr, stream);
  gemm<false, true>(dis, hW1, hb1, o1, GNUM, EMBD, 128, nullptr, nullptr, stream);
  gemm<false, true>(o1, hW2, hb2, o2, GNUM, 128, 128, nullptr, nullptr, stream);
  gemm<false, false>(o2, hW3, hb3, out, GNUM, 128, 128, nullptr, nullptr, stream);
}